// Round 3
// baseline (22246.570 us; speedup 1.0000x reference)
//
#include <hip/hip_runtime.h>
#include <hip/hip_bf16.h>
#include <math.h>

#define T_LEN 128
#define BATCH 64
#define IND   512
#define HDIM  256
#define NS    8
#define H4    1024
#define NTHR  512

typedef unsigned long long ull;
typedef unsigned int uint;
typedef unsigned short ushort;

// ---- LLC-coherent accessors (bypass per-XCD L2): agent-scope relaxed atomics ----
__device__ __forceinline__ float gload(const float* p) {
  return __hip_atomic_load(p, __ATOMIC_RELAXED, __HIP_MEMORY_SCOPE_AGENT);
}
__device__ __forceinline__ float2 gload2(const float* p) {
  ull v = __hip_atomic_load((const ull*)p, __ATOMIC_RELAXED, __HIP_MEMORY_SCOPE_AGENT);
  return __builtin_bit_cast(float2, v);
}
__device__ __forceinline__ void gstore(float* p, float v) {
  __hip_atomic_store(p, v, __ATOMIC_RELAXED, __HIP_MEMORY_SCOPE_AGENT);
}
__device__ __forceinline__ void gstore2(float* p, float a, float b) {
  float2 t = make_float2(a, b);
  __hip_atomic_store((ull*)p, __builtin_bit_cast(ull, t), __ATOMIC_RELAXED, __HIP_MEMORY_SCOPE_AGENT);
}

__device__ __forceinline__ float2 bf2(uint u) {
  return make_float2(__uint_as_float(u << 16), __uint_as_float(u & 0xffff0000u));
}
// 8 bf16 weights vs 8 fp32 A values -> acc
__device__ __forceinline__ void fma8(float& acc, float4 x0, float4 x1, uint4 u) {
  float2 wA = bf2(u.x), wB = bf2(u.y), wC = bf2(u.z), wD = bf2(u.w);
  acc += x0.x * wA.x + x0.y * wA.y + x0.z * wB.x + x0.w * wB.y
       + x1.x * wC.x + x1.y * wC.y + x1.z * wD.x + x1.w * wD.y;
}

// fast tanh via hw exp: tanh(x) = (e^{2x}-1)/(e^{2x}+1); clamp avoids inf/inf
__device__ __forceinline__ float ftanh(float x) {
  float xc = fminf(fmaxf(x, -9.f), 9.f);
  float t = __expf(2.f * xc);
  return (t - 1.f) * __builtin_amdgcn_rcpf(t + 1.f);
}

// ---- per-cluster barrier primitives ----
__device__ __forceinline__ void cbar_signal(int* flags, int cg, int ph) {
  asm volatile("s_waitcnt vmcnt(0)" ::: "memory");
  __syncthreads();
  if (threadIdx.x == 0)
    __hip_atomic_store(flags + cg, ph, __ATOMIC_RELAXED, __HIP_MEMORY_SCOPE_AGENT);
}
__device__ __forceinline__ void cbar_wait(int* flags, int ph) {
  if (threadIdx.x < 64) {
    while (__hip_atomic_load(flags + threadIdx.x, __ATOMIC_RELAXED, __HIP_MEMORY_SCOPE_AGENT) < ph)
      __builtin_amdgcn_s_sleep(1);
  }
  __syncthreads();
}
// wait only on blocks [lo, hi)
__device__ __forceinline__ void cbar_wait_range(int* flags, int ph, int lo, int hi) {
  if ((int)threadIdx.x >= lo && (int)threadIdx.x < hi) {
    while (__hip_atomic_load(flags + threadIdx.x, __ATOMIC_RELAXED, __HIP_MEMORY_SCOPE_AGENT) < ph)
      __builtin_amdgcn_s_sleep(1);
  }
  __syncthreads();
}

extern "C" __global__ void init_ctrl(int* ctrl) {
  int t = blockIdx.x * blockDim.x + threadIdx.x;
  if (t < 1024) ctrl[t] = 0;
}

// ---------------- Xp = tanh(LN(X @ W_proj + b)) ----------------
extern "C" __global__ __launch_bounds__(256) void xp_kernel(
    const float* __restrict__ X, const float* __restrict__ Wp, const float* __restrict__ bp,
    const float* __restrict__ lns, const float* __restrict__ lnb, float* __restrict__ out_xp)
{
  __shared__ float Xs[8 * IND];
  __shared__ float Ys[8 * HDIM];
  const int tid = threadIdx.x;
  const size_t base = (size_t)blockIdx.x * 8;
  const float* Xb = X + base * IND;
  for (int e = tid; e < 8 * IND / 4; e += 256) ((float4*)Xs)[e] = ((const float4*)Xb)[e];
  __syncthreads();
  float acc[8];
#pragma unroll
  for (int r = 0; r < 8; ++r) acc[r] = 0.f;
  for (int k = 0; k < IND; ++k) {
    float wv = Wp[k * HDIM + tid];
#pragma unroll
    for (int r = 0; r < 8; ++r) acc[r] += Xs[r * IND + k] * wv;
  }
  float bpv = bp[tid];
#pragma unroll
  for (int r = 0; r < 8; ++r) Ys[r * HDIM + tid] = acc[r] + bpv;
  __syncthreads();
  int w = tid >> 6, lane = tid & 63;
  for (int rr = 0; rr < 2; ++rr) {
    int r = w * 2 + rr;
    float v[4]; float s1 = 0.f, s2 = 0.f;
#pragma unroll
    for (int e = 0; e < 4; ++e) { v[e] = Ys[r * HDIM + lane + 64 * e]; s1 += v[e]; s2 += v[e] * v[e]; }
#pragma unroll
    for (int off = 32; off > 0; off >>= 1) { s1 += __shfl_xor(s1, off, 64); s2 += __shfl_xor(s2, off, 64); }
    float m = s1 / 256.f;
    float iv = rsqrtf(s2 / 256.f - m * m + 1e-5f);
#pragma unroll
    for (int e = 0; e < 4; ++e) {
      int hd = lane + 64 * e;
      out_xp[(base + r) * HDIM + hd] = tanhf((v[e] - m) * iv * lns[hd] + lnb[hd]);
    }
  }
}

// ws float layout: [0..1023] int flags (cluster rg: ints [rg*64, rg*64+64));
// data base = 1024; per cluster rg (4 clusters), size 135168:
//   QPRE +0 (4096), KPRE +4096 (32768), MB0 +36864, MB1 +69632,
//   Z1c +102400 (16384), Z2c +118784 (16384)

// ---------------- main recurrent kernel: 4 clusters x 64 blocks ----------------
extern "C" __global__ __launch_bounds__(NTHR, 1) void omr_main(
    const float* __restrict__ Xp,
    const float* __restrict__ Wq, const float* __restrict__ bq,
    const float* __restrict__ lnqs, const float* __restrict__ lnqb,
    const float* __restrict__ Wk, const float* __restrict__ bk,
    const float* __restrict__ lnks, const float* __restrict__ lnkb,
    const float* __restrict__ Wbeta, const float* __restrict__ bbeta,
    const float* __restrict__ W1, const float* __restrict__ b1,
    const float* __restrict__ W2, const float* __restrict__ b2,
    const float* __restrict__ lns, const float* __restrict__ lnb,
    float* __restrict__ mem_out, float* __restrict__ probs_out, float* __restrict__ ws)
{
  const int tid = threadIdx.x;
  const int cg = blockIdx.x & 63;   // column group
  const int rg = blockIdx.x >> 6;   // cluster (4 clusters x 16 batch rows)
  const int ZC0 = cg * 16;          // z1/z2 cols owned
  const int QC0 = cg * 4;           // q/k/h cols owned
  const int w = tid >> 6, lane = tid & 63;
  const int rl = lane >> 3, cl = lane & 7;   // 8x8 lane grid; outputs (rl,rl+8)x(cl,cl+8)

  // LDS ~140 KB, all hot GEMM strides ≡ 4 mod 32 banks (conflict-free 8-quad spread)
  __shared__ ushort W1b[16 * 520];    // bf16 W1 col slice
  __shared__ ushort W2b[16 * 1032];   // bf16 W2 col slice
  __shared__ float hlocS[16 * 260];   // current h rows
  __shared__ float AstS[16 * 260];    // Mn(ci) staging
  __shared__ float AzA[16 * 260];     // z1 quarter staging buf A / P1 qln
  __shared__ float AzB[16 * 260];     // z1 quarter staging buf B
  __shared__ float redS[8 * 260];     // split-K partials
  __shared__ float LNS_[256], LNB_[256], LNKS_[256], LNKB_[256], Wbs[256];
  __shared__ float WQS[4 * 260], WKS[4 * 260];   // persistent Wq/Wk own-col slices
  __shared__ float cpS[128], rcpS[128], betaS[128];
  __shared__ float b1s[16], b2s[16], bqS[4], bkS[4], bbetaS[1];

  float* cl_   = ws + 1024 + (size_t)rg * 135168;
  float* QPRE  = cl_;
  float* KPRE  = cl_ + 4096;
  float* MB0   = cl_ + 36864;
  float* MB1   = cl_ + 69632;
  float* Z1c   = cl_ + 102400;
  float* Z2c   = cl_ + 118784;
  int*   flags = (int*)ws + rg * 64;

  // ---- resident weights / params ----
  for (int e = tid; e < 16 * 512; e += NTHR) {
    int k = e >> 4, c = e & 15;
    __hip_bfloat16 h = __float2bfloat16(W1[(size_t)k * H4 + ZC0 + c]);
    W1b[c * 520 + k] = *reinterpret_cast<ushort*>(&h);
  }
  for (int e = tid; e < 16 * 1024; e += NTHR) {
    int k = e >> 4, c = e & 15;
    __hip_bfloat16 h = __float2bfloat16(W2[(size_t)k * H4 + ZC0 + c]);
    W2b[c * 1032 + k] = *reinterpret_cast<ushort*>(&h);
  }
  for (int e = tid; e < 2048; e += NTHR) {
    int s = e >> 10, c = (e >> 8) & 3, k = e & 255;
    (s ? WKS : WQS)[c * 260 + k] = (s ? Wk : Wq)[k * HDIM + QC0 + c];
  }
  if (tid < 256) {
    LNS_[tid] = lns[tid];  LNB_[tid] = lnb[tid];
    LNKS_[tid] = lnks[tid]; LNKB_[tid] = lnkb[tid];
    Wbs[tid] = Wbeta[tid];
  }
  if (tid < 16) { b1s[tid] = b1[ZC0 + tid]; b2s[tid] = b2[ZC0 + tid]; }
  if (tid < 4)  { bqS[tid] = bq[QC0 + tid]; bkS[tid] = bk[QC0 + tid]; }
  if (tid == 0) bbetaS[0] = bbeta[0];

  // ---- Z1 GEMM halves: each of 8 waves does 32 k of the given 256-k half ----
  auto z1Half = [&](const float* Ap, int kwBase, float& a00, float& a01, float& a10, float& a11) {
    const int kb = w * 32;
#pragma unroll
    for (int kk = 0; kk < 32; kk += 8) {
      const int ka = kb + kk, kw = kwBase + kb + kk;
      float4 x0 = *(const float4*)&Ap[rl * 260 + ka];
      float4 x1 = *(const float4*)&Ap[rl * 260 + ka + 4];
      float4 y0 = *(const float4*)&Ap[(rl + 8) * 260 + ka];
      float4 y1 = *(const float4*)&Ap[(rl + 8) * 260 + ka + 4];
      uint4 u0 = *(const uint4*)&W1b[cl * 520 + kw];
      uint4 u1 = *(const uint4*)&W1b[(cl + 8) * 520 + kw];
      fma8(a00, x0, x1, u0); fma8(a01, x0, x1, u1);
      fma8(a10, y0, y1, u0); fma8(a11, y0, y1, u1);
    }
  };
  auto z1Finish = [&](float a00, float a01, float a10, float a11) {
    redS[w * 260 + rl * 16 + cl] = a00;
    redS[w * 260 + rl * 16 + cl + 8] = a01;
    redS[w * 260 + (rl + 8) * 16 + cl] = a10;
    redS[w * 260 + (rl + 8) * 16 + cl + 8] = a11;
    __syncthreads();
    if (tid < 128) {
      int r = tid >> 3, c0 = (tid & 7) * 2;
      float v0 = 0.f, v1 = 0.f;
#pragma unroll
      for (int w2 = 0; w2 < 8; ++w2) {
        v0 += redS[w2 * 260 + r * 16 + c0];
        v1 += redS[w2 * 260 + r * 16 + c0 + 1];
      }
      gstore2(Z1c + r * H4 + ZC0 + c0, fmaxf(v0 + b1s[c0], 0.f), fmaxf(v1 + b1s[c0 + 1], 0.f));
    }
  };

  // ---- t=0 init ----
  {
    int e = cg * 512 + tid;            // 32768 per cluster
    gstore(MB0 + e, 0.f);
    int r = e >> 11, hd = e & 255;
    int b = rg * 16 + r;
    gstore(mem_out + ((size_t)b * NS + ((e >> 8) & 7)) * HDIM + hd, Xp[(size_t)b * HDIM + hd]);
    if (cg == 0 && tid < 128) gstore(probs_out + rg * 128 + tid, 0.f);
  }
  // prestage hlocS = Xp[t=1]
  for (int e = tid; e < 1024; e += NTHR) {
    int r = e >> 6, c4 = (e & 63) * 4;
    *(float4*)&hlocS[r * 260 + c4] = *(const float4*)&Xp[((size_t)BATCH + rg * 16 + r) * HDIM + c4];
  }
  __syncthreads();
  // S1a for t=1 (cM(0) rows = Xp[0], all slots equal), using persistent WQS/WKS
  if (tid < 32) {
    bool isq = tid < 16;
    int row = tid & 15;
    const float* A = Xp + (size_t)((isq ? BATCH : 0) + rg * 16 + row) * HDIM;
    const float* Wl = isq ? WQS : WKS;
    float d[4] = {0, 0, 0, 0};
    for (int k = 0; k < 256; k += 4) {
      float4 a = *(const float4*)(A + k);
#pragma unroll
      for (int c = 0; c < 4; ++c) {
        const float* Wc = Wl + c * 260;
        d[c] += a.x * Wc[k] + a.y * Wc[k + 1] + a.z * Wc[k + 2] + a.w * Wc[k + 3];
      }
    }
#pragma unroll
    for (int c = 0; c < 4; ++c) {
      if (isq) gstore(QPRE + row * HDIM + QC0 + c, d[c] + bqS[c]);
      else { float vk = d[c] + bkS[c]; for (int s = 0; s < NS; ++s) gstore(KPRE + (row * NS + s) * HDIM + QC0 + c, vk); }
    }
  }
  int ph = 0;
  ++ph; cbar_signal(flags, cg, ph); cbar_wait(flags, ph);

  // ================= time loop =================
  for (int t = 1; t < T_LEN; ++t) {
    const size_t tb = (size_t)t * BATCH;
    const bool lastT = (t == T_LEN - 1);
    const float* memPrev = mem_out + (size_t)(t - 1) * BATCH * NS * HDIM;
    float* memCur = mem_out + tb * NS * HDIM;
    const float* probsPrev = probs_out + (size_t)(t - 1) * BATCH * NS;
    float* probsCur = probs_out + tb * NS;
    float* MbOld = ((t - 1) & 1) ? MB1 : MB0;
    float* MbNew = (t & 1) ? MB1 : MB0;
    const int r5 = tid >> 5, u5 = tid & 31, hd0 = u5 * 8;

    // ---------- P1 ----------
    {
      // (1) q layernorm -> AzA[r5*260 + hd]
      float q[8]; float s1 = 0.f, s2 = 0.f;
#pragma unroll
      for (int j = 0; j < 4; ++j) {
        float2 v = gload2(QPRE + r5 * HDIM + hd0 + 2 * j);
        q[2 * j] = v.x; q[2 * j + 1] = v.y;
        s1 += v.x + v.y; s2 += v.x * v.x + v.y * v.y;
      }
#pragma unroll
      for (int m = 1; m < 32; m <<= 1) { s1 += __shfl_xor(s1, m, 64); s2 += __shfl_xor(s2, m, 64); }
      float mean = s1 * (1.f / 256.f);
      float inv = rsqrtf(s2 * (1.f / 256.f) - mean * mean + 1e-5f);
#pragma unroll
      for (int j = 0; j < 8; ++j)
        AzA[r5 * 260 + hd0 + j] = (q[j] - mean) * inv * lnqs[hd0 + j] + lnqb[hd0 + j];
    }
    __syncthreads();
    {
      // (2) k layernorm + beta (redundant per block; 4 threads/k-row)
      int kr = tid >> 2, u4 = tid & 3, rr = kr >> 3;
      const float* kp = KPRE + kr * HDIM + u4 * 64;
      float kv[64]; float s1 = 0.f, s2 = 0.f;
#pragma unroll
      for (int e = 0; e < 32; ++e) {
        float2 v = gload2(kp + 2 * e);
        kv[2 * e] = v.x; kv[2 * e + 1] = v.y;
        s1 += v.x + v.y; s2 += v.x * v.x + v.y * v.y;
      }
      s1 += __shfl_xor(s1, 1, 64); s1 += __shfl_xor(s1, 2, 64);
      s2 += __shfl_xor(s2, 1, 64); s2 += __shfl_xor(s2, 2, 64);
      float mean = s1 * (1.f / 256.f);
      float inv = rsqrtf(s2 * (1.f / 256.f) - mean * mean + 1e-5f);
      float dot = 0.f;
#pragma unroll
      for (int e = 0; e < 64; ++e) {
        int hd = u4 * 64 + e;
        float kl = (kv[e] - mean) * inv * LNKS_[hd] + LNKB_[hd];
        float rv = fmaxf(AzA[rr * 260 + hd] + kl, 0.f);
        dot += rv * Wbs[hd];
      }
      dot += __shfl_xor(dot, 1, 64); dot += __shfl_xor(dot, 2, 64);
      if (u4 == 0) betaS[kr] = (dot + bbetaS[0]) * 0.0625f;
    }
    __syncthreads();
    // (3) softmax + mask + p/cp/rcp (redundant; 16 threads)
    if (tid < 16) {
      int r = tid, b = rg * 16 + r;
      float pp[8], pcp[8], run = 0.f;
#pragma unroll
      for (int s = 0; s < 8; s += 2) {
        float2 v = gload2(probsPrev + b * NS + s);
        pp[s] = v.x; pp[s + 1] = v.y;
      }
#pragma unroll
      for (int s = 0; s < 8; ++s) { run += pp[s]; pcp[s] = run; }
      float bmax = betaS[r * 8];
#pragma unroll
      for (int s = 1; s < 8; ++s) bmax = fmaxf(bmax, betaS[r * 8 + s]);
      float xm[8], ssum = 0.f;
#pragma unroll
      for (int s = 0; s < 8; ++s) {
        float mi;
        if (s < 7) { float cv = pcp[s + 1]; mi = (cv < 1e-5f) ? 0.f : cv; }
        else mi = 1.f;
        xm[s] = __expf(betaS[r * 8 + s] - bmax) * mi;
        ssum += fabsf(xm[s]);
      }
      float denom = fmaxf(ssum, 1e-12f);
      float run2 = 0.f, pn[8];
#pragma unroll
      for (int s = 0; s < 8; ++s) {
        pn[s] = xm[s] / denom; run2 += pn[s];
        cpS[r * 8 + s] = run2;
        if (cg == r) gstore(probsCur + b * NS + s, pn[s]);
      }
      float run3 = 0.f;
#pragma unroll
      for (int s = 7; s >= 0; --s) { run3 += pn[s]; rcpS[r * 8 + s] = run3; }
    }
    __syncthreads();
    {
      // (4) M-state owner update (own 4 cols, all 16 rows x 8 slots)
      int r = tid >> 5, s = (tid >> 2) & 7, c = tid & 3;
      int hd = QC0 + c;
      int idx = (r * NS + s) * HDIM + hd;
      float rc = rcpS[r * 8 + s];
      float mo = gload(MbOld + idx);
      float cm = gload(memPrev + ((size_t)(rg * 16 + r) * NS + s) * HDIM + hd);
      gstore(MbNew + idx, mo * (1.f - rc) + cm * rc);
    }
    {
      // (5) stage Mn(slot0)=blend(MbOld,memPrev); hlocS=Xp[t] was prestaged
      float rc0 = rcpS[r5 * 8];
#pragma unroll
      for (int jj = 0; jj < 2; ++jj) {
        int k = u5 * 4 + jj * 128;
        float2 m0 = gload2(MbOld + (r5 * NS) * HDIM + k);
        float2 m1 = gload2(MbOld + (r5 * NS) * HDIM + k + 2);
        float2 c0 = gload2(memPrev + ((size_t)(rg * 16 + r5) * NS) * HDIM + k);
        float2 c1 = gload2(memPrev + ((size_t)(rg * 16 + r5) * NS) * HDIM + k + 2);
        *(float4*)&AstS[r5 * 260 + k] = make_float4(
            m0.x * (1.f - rc0) + c0.x * rc0, m0.y * (1.f - rc0) + c0.y * rc0,
            m1.x * (1.f - rc0) + c1.x * rc0, m1.y * (1.f - rc0) + c1.y * rc0);
      }
    }
    __syncthreads();
    {
      float a00 = 0, a01 = 0, a10 = 0, a11 = 0;
      z1Half(AstS, 256, a00, a01, a10, a11);
      z1Half(hlocS, 0, a00, a01, a10, a11);
      z1Finish(a00, a01, a10, a11);
    }
    ++ph; cbar_signal(flags, cg, ph);   // P1 signal; wait deferred into Z2 quarters

    // ---------- cells ----------
    for (int ci = 0; ci < NS; ++ci) {
      const int phRdy = ph;   // Z1(ci)-ready phase (P1 for ci=0, B(ci-1) else)
      // ---- Z2(ci): quarter-pipelined over Z1 cols with partial barrier waits ----
      {
        float za00 = 0, za01 = 0, za10 = 0, za11 = 0;
        const float* zr = Z1c + r5 * H4;
        float2 pf[4];
        // prologue: quarter 0
        cbar_wait_range(flags, phRdy, 0, 16);
#pragma unroll
        for (int jj = 0; jj < 2; ++jj) {
          int k = u5 * 4 + jj * 128;
          pf[jj * 2] = gload2(zr + k); pf[jj * 2 + 1] = gload2(zr + k + 2);
        }
#pragma unroll
        for (int jj = 0; jj < 2; ++jj) {
          int k = u5 * 4 + jj * 128;
          *(float4*)&AzA[r5 * 260 + k] = make_float4(pf[jj * 2].x, pf[jj * 2].y, pf[jj * 2 + 1].x, pf[jj * 2 + 1].y);
        }
        __syncthreads();
#pragma unroll
        for (int ch = 0; ch < 4; ++ch) {
          float* bufCur = (ch & 1) ? AzB : AzA;
          float* bufNxt = (ch & 1) ? AzA : AzB;
          if (ch < 3) {
            cbar_wait_range(flags, phRdy, (ch + 1) * 16, (ch + 2) * 16);
#pragma unroll
            for (int jj = 0; jj < 2; ++jj) {
              int k = u5 * 4 + jj * 128;
              pf[jj * 2]     = gload2(zr + (ch + 1) * 256 + k);
              pf[jj * 2 + 1] = gload2(zr + (ch + 1) * 256 + k + 2);
            }
          }
          const int kb = w * 32, kw0 = ch * 256 + kb;
#pragma unroll
          for (int kk = 0; kk < 32; kk += 8) {
            float4 x0 = *(const float4*)&bufCur[rl * 260 + kb + kk];
            float4 x1 = *(const float4*)&bufCur[rl * 260 + kb + kk + 4];
            float4 y0 = *(const float4*)&bufCur[(rl + 8) * 260 + kb + kk];
            float4 y1 = *(const float4*)&bufCur[(rl + 8) * 260 + kb + kk + 4];
            uint4 u0 = *(const uint4*)&W2b[cl * 1032 + kw0 + kk];
            uint4 u1 = *(const uint4*)&W2b[(cl + 8) * 1032 + kw0 + kk];
            fma8(za00, x0, x1, u0); fma8(za01, x0, x1, u1);
            fma8(za10, y0, y1, u0); fma8(za11, y0, y1, u1);
          }
          if (ch < 3) {
#pragma unroll
            for (int jj = 0; jj < 2; ++jj) {
              int k = u5 * 4 + jj * 128;
              *(float4*)&bufNxt[r5 * 260 + k] = make_float4(pf[jj * 2].x, pf[jj * 2].y, pf[jj * 2 + 1].x, pf[jj * 2 + 1].y);
            }
          }
          __syncthreads();
        }
        redS[w * 260 + rl * 16 + cl] = za00;
        redS[w * 260 + rl * 16 + cl + 8] = za01;
        redS[w * 260 + (rl + 8) * 16 + cl] = za10;
        redS[w * 260 + (rl + 8) * 16 + cl + 8] = za11;
        __syncthreads();
        if (tid < 128) {
          int r = tid >> 3, c0 = (tid & 7) * 2;
          float v0 = 0.f, v1 = 0.f;
#pragma unroll
          for (int w2 = 0; w2 < 8; ++w2) {
            v0 += redS[w2 * 260 + r * 16 + c0];
            v1 += redS[w2 * 260 + r * 16 + c0 + 1];
          }
          gstore2(Z2c + r * H4 + ZC0 + c0, v0 + b2s[c0], v1 + b2s[c0 + 1]);
        }
      }
      // preload hi (AstS slot ci) into regs so AstS can be restaged in the window
      float hiv[8];
      {
        float4 hA = *(const float4*)&AstS[r5 * 260 + hd0];
        float4 hB = *(const float4*)&AstS[r5 * 260 + hd0 + 4];
        hiv[0] = hA.x; hiv[1] = hA.y; hiv[2] = hA.z; hiv[3] = hA.w;
        hiv[4] = hB.x; hiv[5] = hB.y; hiv[6] = hB.z; hiv[7] = hB.w;
      }
      ++ph; cbar_signal(flags, cg, ph);   // signal A(ci)
      // ======== window A: overlap with peers' Z2 completion ========
      if (ci < 7) {
        // restage AstS = MbNew slot ci+1 (fully blended in P1)
#pragma unroll
        for (int jj = 0; jj < 2; ++jj) {
          int k = u5 * 4 + jj * 128;
          float2 a = gload2(MbNew + (r5 * NS + ci + 1) * HDIM + k);
          float2 b = gload2(MbNew + (r5 * NS + ci + 1) * HDIM + k + 2);
          *(float4*)&AstS[r5 * 260 + k] = make_float4(a.x, a.y, b.x, b.y);
        }
      } else if (!lastT && w == 7) {
        // S1a KPRE(s=6): memCur[6] visible since wait on B(6) in Z2(7) quarters
        const int rr = (tid >> 2) & 15, part = tid & 3, k0 = part * 64;
        const float* A = memCur + ((size_t)(rg * 16 + rr) * NS + 6) * HDIM + k0;
        float d0 = 0, d1 = 0, d2 = 0, d3 = 0;
#pragma unroll
        for (int k = 0; k < 64; k += 2) {
          float2 a = gload2(A + k);
          const float* q0 = WKS + k0 + k;
          d0 += a.x * q0[0]   + a.y * q0[1];
          d1 += a.x * q0[260] + a.y * q0[261];
          d2 += a.x * q0[520] + a.y * q0[521];
          d3 += a.x * q0[780] + a.y * q0[781];
        }
        d0 += __shfl_xor(d0, 1, 64); d0 += __shfl_xor(d0, 2, 64);
        d1 += __shfl_xor(d1, 1, 64); d1 += __shfl_xor(d1, 2, 64);
        d2 += __shfl_xor(d2, 1, 64); d2 += __shfl_xor(d2, 2, 64);
        d3 += __shfl_xor(d3, 1, 64); d3 += __shfl_xor(d3, 2, 64);
        if (part == 0) {
          float* kp = KPRE + (rr * NS + 6) * HDIM + QC0;
          gstore(kp + 0, d0 + bkS[0]);
          gstore(kp + 1, d1 + bkS[1]);
          gstore(kp + 2, d2 + bkS[2]);
          gstore(kp + 3, d3 + bkS[3]);
        }
      }
      __syncthreads();
      float b00 = 0, b01 = 0, b10 = 0, b11 = 0;
      if (ci < 7) z1Half(AstS, 256, b00, b01, b10, b11);  // Mn-half of Z1(ci+1)

      // ---- H(ci): split wait A — cc providers (48..63) first, then g (0..47) ----
      {
        const float* z2r = Z2c + r5 * H4;
        cbar_wait_range(flags, ph, 48, 64);
        float cc[8]; float s1 = 0.f, s2 = 0.f;
#pragma unroll
        for (int j = 0; j < 4; ++j) {
          float2 v = gload2(z2r + 768 + hd0 + 2 * j);
          cc[2 * j] = v.x; cc[2 * j + 1] = v.y;
          s1 += v.x + v.y; s2 += v.x * v.x + v.y * v.y;
        }
#pragma unroll
        for (int m = 1; m < 32; m <<= 1) { s1 += __shfl_xor(s1, m, 64); s2 += __shfl_xor(s2, m, 64); }
        float mean = s1 * (1.f / 256.f);
        float inv = rsqrtf(s2 * (1.f / 256.f) - mean * mean + 1e-5f);
        cbar_wait_range(flags, ph, 0, 48);
        float g[24];
#pragma unroll
        for (int j = 0; j < 12; ++j) {
          float2 v = gload2(z2r + hd0 * 3 + 2 * j);
          g[2 * j] = v.x; g[2 * j + 1] = v.y;
        }
        float4 viA = *(const float4*)&hlocS[r5 * 260 + hd0];
        float4 viB = *(const float4*)&hlocS[r5 * 260 + hd0 + 4];
        float4 xpA = *(const float4*)&Xp[(tb + rg * 16 + r5) * HDIM + hd0];
        float4 xpB = *(const float4*)&Xp[(tb + rg * 16 + r5) * HDIM + hd0 + 4];
        float viv[8] = {viA.x, viA.y, viA.z, viA.w, viB.x, viB.y, viB.z, viB.w};
        float xpv[8] = {xpA.x, xpA.y, xpA.z, xpA.w, xpB.x, xpB.y, xpB.z, xpB.w};
        float cp = cpS[r5 * 8 + ci];
        float hn[8];
#pragma unroll
        for (int j = 0; j < 8; ++j) {
          int hd = hd0 + j;
          float z0 = g[3 * j], z1v = g[3 * j + 1], z2g = g[3 * j + 2];
          float gm = fmaxf(z0, fmaxf(z1v, z2g));
          float e0 = __expf(z0 - gm), e1 = __expf(z1v - gm), e2 = __expf(z2g - gm);
          float act = ftanh((cc[j] - mean) * inv * LNS_[hd] + LNB_[hd]);
          float hc = (e0 * viv[j] + e1 * hiv[j] + e2 * act) * __builtin_amdgcn_rcpf(e0 + e1 + e2);
          hn[j] = xpv[j] * (1.f - cp) + hc * cp;
        }
        *(float4*)&hlocS[r5 * 260 + hd0] = make_float4(hn[0], hn[1], hn[2], hn[3]);
        *(float4*)&hlocS[r5 * 260 + hd0 + 4] = make_float4(hn[4], hn[5], hn[6], hn[7]);
        if (hd0 == (QC0 & ~7)) {
          int o4 = QC0 & 4;
          float* mp = memCur + ((size_t)(rg * 16 + r5) * NS + ci) * HDIM + QC0;
          gstore2(mp, hn[o4], hn[o4 + 1]);
          gstore2(mp + 2, hn[o4 + 2], hn[o4 + 3]);
        }
      }
      __syncthreads();

      if (ci < 7) {
        // h-half of Z1(ci+1), combine with window partials
        z1Half(hlocS, 0, b00, b01, b10, b11);
        z1Finish(b00, b01, b10, b11);
      } else if (!lastT && w == 7) {
        // KPRE row s=7 for t+1 from final h (local in hlocS) — must be pre-signal
        const int rr = (tid >> 2) & 15, part = tid & 3, k0 = part * 64;
        const float* A = &hlocS[rr * 260 + k0];
        float d0 = 0, d1 = 0, d2 = 0, d3 = 0;
#pragma unroll
        for (int k = 0; k < 64; k += 4) {
          float4 a = *(const float4*)(A + k);
          const float* q0 = WKS + k0 + k;
          d0 += a.x * q0[0]   + a.y * q0[1]   + a.z * q0[2]   + a.w * q0[3];
          d1 += a.x * q0[260] + a.y * q0[261] + a.z * q0[262] + a.w * q0[263];
          d2 += a.x * q0[520] + a.y * q0[521] + a.z * q0[522] + a.w * q0[523];
          d3 += a.x * q0[780] + a.y * q0[781] + a.z * q0[782] + a.w * q0[783];
        }
        d0 += __shfl_xor(d0, 1, 64); d0 += __shfl_xor(d0, 2, 64);
        d1 += __shfl_xor(d1, 1, 64); d1 += __shfl_xor(d1, 2, 64);
        d2 += __shfl_xor(d2, 1, 64); d2 += __shfl_xor(d2, 2, 64);
        d3 += __shfl_xor(d3, 1, 64); d3 += __shfl_xor(d3, 2, 64);
        if (part == 0) {
          float* kp = KPRE + (rr * NS + 7) * HDIM + QC0;
          gstore(kp + 0, d0 + bkS[0]);
          gstore(kp + 1, d1 + bkS[1]);
          gstore(kp + 2, d2 + bkS[2]);
          gstore(kp + 3, d3 + bkS[3]);
        }
      }
      ++ph; cbar_signal(flags, cg, ph);   // signal B(ci)
      // ======== window B: S1a(t+1) pieces (drained by NEXT signal A) ========
      if (!lastT) {
        if (w == 7 && ci == 0) {
          // QPRE(t+1): needs only Xp[t+1]
          const int rr = (tid >> 2) & 15, part = tid & 3, k0 = part * 64;
          const float* A = Xp + ((size_t)(t + 1) * BATCH + rg * 16 + rr) * HDIM + k0;
          float d0 = 0, d1 = 0, d2 = 0, d3 = 0;
#pragma unroll
          for (int k = 0; k < 64; k += 4) {
            float4 a = *(const float4*)(A + k);
            const float* q0 = WQS + k0 + k;
            d0 += a.x * q0[0]   + a.y * q0[1]   + a.z * q0[2]   + a.w * q0[3];
            d1 += a.x * q0[260] + a.y * q0[261] + a.z * q0[262] + a.w * q0[263];
            d2 += a.x * q0[520] + a.y * q0[521] + a.z * q0[522] + a.w * q0[523];
            d3 += a.x * q0[780] + a.y * q0[781] + a.z * q0[782] + a.w * q0[783];
          }
          d0 += __shfl_xor(d0, 1, 64); d0 += __shfl_xor(d0, 2, 64);
          d1 += __shfl_xor(d1, 1, 64); d1 += __shfl_xor(d1, 2, 64);
          d2 += __shfl_xor(d2, 1, 64); d2 += __shfl_xor(d2, 2, 64);
          d3 += __shfl_xor(d3, 1, 64); d3 += __shfl_xor(d3, 2, 64);
          if (part == 0) {
            gstore(QPRE + rr * HDIM + QC0 + 0, d0 + bqS[0]);
            gstore(QPRE + rr * HDIM + QC0 + 1, d1 + bqS[1]);
            gstore(QPRE + rr * HDIM + QC0 + 2, d2 + bqS[2]);
            gstore(QPRE + rr * HDIM + QC0 + 3, d3 + bqS[3]);
          }
        } else if (w == 7 && ci >= 1 && ci < 7) {
          // KPRE(s=ci-1): memCur[ci-1] visible since wait on B(ci-1) in Z2(ci)
          const int s = ci - 1;
          const int rr = (tid >> 2) & 15, part = tid & 3, k0 = part * 64;
          const float* A = memCur + ((size_t)(rg * 16 + rr) * NS + s) * HDIM + k0;
          float d0 = 0, d1 = 0, d2 = 0, d3 = 0;
#pragma unroll
          for (int k = 0; k < 64; k += 2) {
            float2 a = gload2(A + k);
            const float* q0 = WKS + k0 + k;
            d0 += a.x * q0[0]   + a.y * q0[1];
            d1 += a.x * q0[260] + a.y * q0[261];
            d2 += a.x * q0[520] + a.y * q0[521];
            d3 += a.x * q0[780] + a.y * q0[781];
          }
          d0 += __shfl_xor(d0, 1, 64); d0 += __shfl_xor(d0, 2, 64);
          d1 += __shfl_xor(d1, 1, 64); d1 += __shfl_xor(d1, 2, 64);
          d2 += __shfl_xor(d2, 1, 64); d2 += __shfl_xor(d2, 2, 64);
          d3 += __shfl_xor(d3, 1, 64); d3 += __shfl_xor(d3, 2, 64);
          if (part == 0) {
            float* kp = KPRE + (rr * NS + s) * HDIM + QC0;
            gstore(kp + 0, d0 + bkS[0]);
            gstore(kp + 1, d1 + bkS[1]);
            gstore(kp + 2, d2 + bkS[2]);
            gstore(kp + 3, d3 + bkS[3]);
          }
        } else if (ci == 7) {
          // prestage hlocS = Xp[t+1] for next P1 (local LDS; all threads)
#pragma unroll
          for (int jj = 0; jj < 2; ++jj) {
            int k = u5 * 4 + jj * 128;
            *(float4*)&hlocS[r5 * 260 + k] =
                *(const float4*)&Xp[((size_t)(t + 1) * BATCH + rg * 16 + r5) * HDIM + k];
          }
        }
      }
    }
    // full barrier before next P1 (P1 reads full QPRE/KPRE rows)
    cbar_wait(flags, ph);
  }
}

extern "C" void kernel_launch(void* const* d_in, const int* in_sizes, int n_in,
                              void* d_out, int out_size, void* d_ws, size_t ws_size,
                              hipStream_t stream) {
  (void)in_sizes; (void)n_in; (void)out_size; (void)ws_size;
  const float* X     = (const float*)d_in[0];
  const float* Wp    = (const float*)d_in[3];
  const float* bp    = (const float*)d_in[4];
  const float* lns   = (const float*)d_in[5];
  const float* lnb   = (const float*)d_in[6];
  const float* Wq    = (const float*)d_in[7];
  const float* bq    = (const float*)d_in[8];
  const float* lnqs  = (const float*)d_in[9];
  const float* lnqb  = (const float*)d_in[10];
  const float* Wk    = (const float*)d_in[11];
  const float* bk    = (const float*)d_in[12];
  const float* lnks  = (const float*)d_in[13];
  const float* lnkb  = (const float*)d_in[14];
  const float* Wbeta = (const float*)d_in[15];
  const float* bbeta = (const float*)d_in[16];
  const float* W1    = (const float*)d_in[17];
  const float* b1    = (const float*)d_in[18];
  const float* W2    = (const float*)d_in[19];
  const float* b2    = (const float*)d_in[20];

  float* out       = (float*)d_out;
  float* out_xp    = out;
  float* out_mem   = out + (size_t)T_LEN * BATCH * HDIM;
  float* out_probs = out_mem + (size_t)T_LEN * BATCH * NS * HDIM;
  float* ws        = (float*)d_ws;

  hipLaunchKernelGGL(init_ctrl, dim3(4), dim3(256), 0, stream, (int*)d_ws);
  hipLaunchKernelGGL(xp_kernel, dim3(1024), dim3(256), 0, stream, X, Wp, bp, lns, lnb, out_xp);
  hipLaunchKernelGGL(omr_main, dim3(256), dim3(NTHR), 0, stream,
                     out_xp, Wq, bq, lnqs, lnqb, Wk, bk, lnks, lnkb, Wbeta, bbeta,
                     W1, b1, W2, b2, lns, lnb, out_mem, out_probs, ws);
}

// Round 4
// 19517.570 us; speedup vs baseline: 1.1398x; 1.1398x over previous
//
#include <hip/hip_runtime.h>
#include <hip/hip_bf16.h>
#include <math.h>

#define T_LEN 128
#define BATCH 64
#define IND   512
#define HDIM  256
#define NS    8
#define H4    1024
#define NTHR  512
#define RPC   8        // rows per cluster (pipeline)
#define CSTRIDE 67584  // floats per cluster in ws

typedef unsigned long long ull;
typedef unsigned int uint;
typedef unsigned short ushort;

// ---- LLC-coherent accessors (bypass per-XCD L2): agent-scope relaxed atomics ----
__device__ __forceinline__ float gload(const float* p) {
  return __hip_atomic_load(p, __ATOMIC_RELAXED, __HIP_MEMORY_SCOPE_AGENT);
}
__device__ __forceinline__ float2 gload2(const float* p) {
  ull v = __hip_atomic_load((const ull*)p, __ATOMIC_RELAXED, __HIP_MEMORY_SCOPE_AGENT);
  return __builtin_bit_cast(float2, v);
}
__device__ __forceinline__ void gstore(float* p, float v) {
  __hip_atomic_store(p, v, __ATOMIC_RELAXED, __HIP_MEMORY_SCOPE_AGENT);
}
__device__ __forceinline__ void gstore2(float* p, float a, float b) {
  float2 t = make_float2(a, b);
  __hip_atomic_store((ull*)p, __builtin_bit_cast(ull, t), __ATOMIC_RELAXED, __HIP_MEMORY_SCOPE_AGENT);
}

__device__ __forceinline__ float2 bf2(uint u) {
  return make_float2(__uint_as_float(u << 16), __uint_as_float(u & 0xffff0000u));
}
// 8 bf16 weights vs 8 fp32 A values -> acc
__device__ __forceinline__ void fma8(float& acc, float4 x0, float4 x1, uint4 u) {
  float2 wA = bf2(u.x), wB = bf2(u.y), wC = bf2(u.z), wD = bf2(u.w);
  acc += x0.x * wA.x + x0.y * wA.y + x0.z * wB.x + x0.w * wB.y
       + x1.x * wC.x + x1.y * wC.y + x1.z * wD.x + x1.w * wD.y;
}

// fast tanh via hw exp
__device__ __forceinline__ float ftanh(float x) {
  float xc = fminf(fmaxf(x, -9.f), 9.f);
  float t = __expf(2.f * xc);
  return (t - 1.f) * __builtin_amdgcn_rcpf(t + 1.f);
}

extern "C" __global__ void init_ctrl(int* ctrl) {
  int t = blockIdx.x * blockDim.x + threadIdx.x;
  if (t < 1024) ctrl[t] = 0;
}

// ---------------- Xp = tanh(LN(X @ W_proj + b)) ----------------
extern "C" __global__ __launch_bounds__(256) void xp_kernel(
    const float* __restrict__ X, const float* __restrict__ Wp, const float* __restrict__ bp,
    const float* __restrict__ lns, const float* __restrict__ lnb, float* __restrict__ out_xp)
{
  __shared__ float Xs[8 * IND];
  __shared__ float Ys[8 * HDIM];
  const int tid = threadIdx.x;
  const size_t base = (size_t)blockIdx.x * 8;
  const float* Xb = X + base * IND;
  for (int e = tid; e < 8 * IND / 4; e += 256) ((float4*)Xs)[e] = ((const float4*)Xb)[e];
  __syncthreads();
  float acc[8];
#pragma unroll
  for (int r = 0; r < 8; ++r) acc[r] = 0.f;
  for (int k = 0; k < IND; ++k) {
    float wv = Wp[k * HDIM + tid];
#pragma unroll
    for (int r = 0; r < 8; ++r) acc[r] += Xs[r * IND + k] * wv;
  }
  float bpv = bp[tid];
#pragma unroll
  for (int r = 0; r < 8; ++r) Ys[r * HDIM + tid] = acc[r] + bpv;
  __syncthreads();
  int w = tid >> 6, lane = tid & 63;
  for (int rr = 0; rr < 2; ++rr) {
    int r = w * 2 + rr;
    float v[4]; float s1 = 0.f, s2 = 0.f;
#pragma unroll
    for (int e = 0; e < 4; ++e) { v[e] = Ys[r * HDIM + lane + 64 * e]; s1 += v[e]; s2 += v[e] * v[e]; }
#pragma unroll
    for (int off = 32; off > 0; off >>= 1) { s1 += __shfl_xor(s1, off, 64); s2 += __shfl_xor(s2, off, 64); }
    float m = s1 / 256.f;
    float iv = rsqrtf(s2 / 256.f - m * m + 1e-5f);
#pragma unroll
    for (int e = 0; e < 4; ++e) {
      int hd = lane + 64 * e;
      out_xp[(base + r) * HDIM + hd] = tanhf((v[e] - m) * iv * lns[hd] + lnb[hd]);
    }
  }
}

// ws float layout: [0..1023] int flags (cluster cl: ints [cl*64, cl*64+64)), 8 clusters;
// data base = 1024; per cluster cl (8 clusters of 8 rows), stride 67584:
//   QPRE +0 (2048), KPRE +2048 (16384), MB0 +18432 (16384), MB1 +34816 (16384),
//   Z1c +51200 (8192), Z2c +59392 (8192)

struct Pipe {
  float *QPRE, *KPRE, *MB0, *MB1, *Z1c, *Z2c;
  int* flags;
  float *hloc, *Ast, *cpS, *rcpS, *betaS;
  int row0;
};

// ---------------- main recurrent kernel: 8 clusters, 2 pipelines per block ----------------
extern "C" __global__ __launch_bounds__(NTHR, 1) void omr_main(
    const float* __restrict__ Xp,
    const float* __restrict__ Wq, const float* __restrict__ bq,
    const float* __restrict__ lnqs, const float* __restrict__ lnqb,
    const float* __restrict__ Wk, const float* __restrict__ bk,
    const float* __restrict__ lnks, const float* __restrict__ lnkb,
    const float* __restrict__ Wbeta, const float* __restrict__ bbeta,
    const float* __restrict__ W1, const float* __restrict__ b1,
    const float* __restrict__ W2, const float* __restrict__ b2,
    const float* __restrict__ lns, const float* __restrict__ lnb,
    float* __restrict__ mem_out, float* __restrict__ probs_out, float* __restrict__ ws)
{
  const int tid = threadIdx.x;
  const int sc = blockIdx.x >> 6;   // supercluster (4), pipes = clusters 2sc, 2sc+1
  const int cg = blockIdx.x & 63;   // column group within supercluster
  const int ZC0 = cg * 16;          // z1/z2 cols owned
  const int QC0 = cg * 4;           // q/k/h cols owned
  const int w = tid >> 6, lane = tid & 63;
  const int rl = lane >> 3, cl = lane & 7;   // 8x8 lane grid: rows rl, cols (cl, cl+8)

  // LDS ~116 KB; GEMM strides ≡ 4 mod 32 banks
  __shared__ ushort W1b[16 * 520];    // bf16 W1 col slice (shared by both pipes)
  __shared__ ushort W2b[16 * 1032];   // bf16 W2 col slice
  __shared__ float hloc0[RPC * 260], hloc1[RPC * 260];
  __shared__ float Ast0[RPC * 260], Ast1[RPC * 260];
  __shared__ float Az0[RPC * 260], Az1[RPC * 260];   // shared staging (time-sliced)
  __shared__ float redS[8 * 132];                    // split-K partials (8x16 tile)
  __shared__ float LNS_[256], LNB_[256], LNKS_[256], LNKB_[256], Wbs[256];
  __shared__ float WQS[4 * 260], WKS[4 * 260];
  __shared__ float cp0[64], cp1[64], rcp0[64], rcp1[64], bet0[64], bet1[64];
  __shared__ float b1s[16], b2s[16], bqS[4], bkS[4], bbetaS[1];

  auto mkPipe = [&](int p, float* hl, float* as, float* cp, float* rcp, float* bet) {
    Pipe P;
    int clid = sc * 2 + p;
    float* base = ws + 1024 + (size_t)clid * CSTRIDE;
    P.QPRE = base; P.KPRE = base + 2048;
    P.MB0 = base + 18432; P.MB1 = base + 34816;
    P.Z1c = base + 51200; P.Z2c = base + 59392;
    P.flags = (int*)ws + clid * 64;
    P.hloc = hl; P.Ast = as; P.cpS = cp; P.rcpS = rcp; P.betaS = bet;
    P.row0 = clid * RPC;
    return P;
  };
  Pipe P0 = mkPipe(0, hloc0, Ast0, cp0, rcp0, bet0);
  Pipe P1 = mkPipe(1, hloc1, Ast1, cp1, rcp1, bet1);

  // ---- resident weights / params ----
  for (int e = tid; e < 16 * 512; e += NTHR) {
    int k = e >> 4, c = e & 15;
    __hip_bfloat16 h = __float2bfloat16(W1[(size_t)k * H4 + ZC0 + c]);
    W1b[c * 520 + k] = *reinterpret_cast<ushort*>(&h);
  }
  for (int e = tid; e < 16 * 1024; e += NTHR) {
    int k = e >> 4, c = e & 15;
    __hip_bfloat16 h = __float2bfloat16(W2[(size_t)k * H4 + ZC0 + c]);
    W2b[c * 1032 + k] = *reinterpret_cast<ushort*>(&h);
  }
  for (int e = tid; e < 2048; e += NTHR) {
    int s = e >> 10, c = (e >> 8) & 3, k = e & 255;
    (s ? WKS : WQS)[c * 260 + k] = (s ? Wk : Wq)[k * HDIM + QC0 + c];
  }
  if (tid < 256) {
    LNS_[tid] = lns[tid];  LNB_[tid] = lnb[tid];
    LNKS_[tid] = lnks[tid]; LNKB_[tid] = lnkb[tid];
    Wbs[tid] = Wbeta[tid];
  }
  if (tid < 16) { b1s[tid] = b1[ZC0 + tid]; b2s[tid] = b2[ZC0 + tid]; }
  if (tid < 4)  { bqS[tid] = bq[QC0 + tid]; bkS[tid] = bk[QC0 + tid]; }
  if (tid == 0) bbetaS[0] = bbeta[0];

  // ---- barrier primitives ----
  auto waitF = [&](int* f, int p) {
    if (tid < 64) {
      while (__hip_atomic_load(f + tid, __ATOMIC_RELAXED, __HIP_MEMORY_SCOPE_AGENT) < p)
        __builtin_amdgcn_s_sleep(1);
    }
    __syncthreads();
  };
  auto sigBoth = [&](int p) {
    asm volatile("s_waitcnt vmcnt(0)" ::: "memory");
    __syncthreads();
    if (tid == 0) __hip_atomic_store(P0.flags + cg, p, __ATOMIC_RELAXED, __HIP_MEMORY_SCOPE_AGENT);
    if (tid == 1) __hip_atomic_store(P1.flags + cg, p, __ATOMIC_RELAXED, __HIP_MEMORY_SCOPE_AGENT);
  };

  // ---- 8-row GEMM helpers ----
  auto z1Half = [&](const float* Ap, int kwBase, float& a00, float& a01) {
    const int kb = w * 32;
#pragma unroll
    for (int kk = 0; kk < 32; kk += 8) {
      const int ka = kb + kk, kw = kwBase + kb + kk;
      float4 x0 = *(const float4*)&Ap[rl * 260 + ka];
      float4 x1 = *(const float4*)&Ap[rl * 260 + ka + 4];
      uint4 u0 = *(const uint4*)&W1b[cl * 520 + kw];
      uint4 u1 = *(const uint4*)&W1b[(cl + 8) * 520 + kw];
      fma8(a00, x0, x1, u0); fma8(a01, x0, x1, u1);
    }
  };
  auto redFinish = [&](float a00, float a01, float* dst, const float* bias, bool doRelu) {
    __syncthreads();                    // protect prior redS readers
    redS[w * 132 + rl * 16 + cl] = a00;
    redS[w * 132 + rl * 16 + cl + 8] = a01;
    __syncthreads();
    if (tid < 64) {
      int r = tid >> 3, c0 = (tid & 7) * 2;
      float v0 = 0.f, v1 = 0.f;
#pragma unroll
      for (int w2 = 0; w2 < 8; ++w2) {
        v0 += redS[w2 * 132 + r * 16 + c0];
        v1 += redS[w2 * 132 + r * 16 + c0 + 1];
      }
      v0 += bias[c0]; v1 += bias[c0 + 1];
      if (doRelu) { v0 = fmaxf(v0, 0.f); v1 = fmaxf(v1, 0.f); }
      gstore2(dst + r * H4 + ZC0 + c0, v0, v1);
    }
  };

  // ---- 4-col projections (wave w = row w; 16 lanes per col) ----
  auto projQ = [&](const float* A /*plain global row*/, float* dst) {
    int col = lane >> 4, kp = lane & 15;
    const float* Wc = WQS + col * 260 + kp * 16;
    const float* Ak = A + kp * 16;
    float d = 0.f;
#pragma unroll
    for (int k4 = 0; k4 < 4; ++k4) {
      float4 a = *(const float4*)(Ak + 4 * k4);
      d += a.x * Wc[4 * k4] + a.y * Wc[4 * k4 + 1] + a.z * Wc[4 * k4 + 2] + a.w * Wc[4 * k4 + 3];
    }
    d += __shfl_xor(d, 1, 64); d += __shfl_xor(d, 2, 64);
    d += __shfl_xor(d, 4, 64); d += __shfl_xor(d, 8, 64);
    if (kp == 0) gstore(dst + col, d + bqS[col]);
  };
  auto projK_G = [&](const float* A /*LLC row (gload)*/, float* dst) {
    int col = lane >> 4, kp = lane & 15;
    const float* Wc = WKS + col * 260 + kp * 16;
    const float* Ak = A + kp * 16;
    float d = 0.f;
#pragma unroll
    for (int k2 = 0; k2 < 8; ++k2) {
      float2 a = gload2(Ak + 2 * k2);
      d += a.x * Wc[2 * k2] + a.y * Wc[2 * k2 + 1];
    }
    d += __shfl_xor(d, 1, 64); d += __shfl_xor(d, 2, 64);
    d += __shfl_xor(d, 4, 64); d += __shfl_xor(d, 8, 64);
    if (kp == 0) gstore(dst + col, d + bkS[col]);
  };
  auto projK_L = [&](const float* A /*LDS row*/, float* dst) {
    int col = lane >> 4, kp = lane & 15;
    const float* Wc = WKS + col * 260 + kp * 16;
    const float* Ak = A + kp * 16;
    float d = 0.f;
#pragma unroll
    for (int k4 = 0; k4 < 4; ++k4) {
      float4 a = *(const float4*)(Ak + 4 * k4);
      d += a.x * Wc[4 * k4] + a.y * Wc[4 * k4 + 1] + a.z * Wc[4 * k4 + 2] + a.w * Wc[4 * k4 + 3];
    }
    d += __shfl_xor(d, 1, 64); d += __shfl_xor(d, 2, 64);
    d += __shfl_xor(d, 4, 64); d += __shfl_xor(d, 8, 64);
    if (kp == 0) gstore(dst + col, d + bkS[col]);
  };

  // ---- t=0 init per pipe ----
  auto initPipe = [&](Pipe& P) {
    if (tid < 256) {
      int e = cg * 256 + tid;          // 16384 floats over 64 blocks
      gstore(P.MB0 + e, 0.f);
      int r = e >> 11, s = (e >> 8) & 7, hd = e & 255;
      gstore(mem_out + ((size_t)(P.row0 + r) * NS + s) * HDIM + hd,
             Xp[(size_t)(P.row0 + r) * HDIM + hd]);
    }
    if (cg == 0 && tid < 64) gstore(probs_out + P.row0 * NS + tid, 0.f);
    {
      int r = tid >> 6, c4 = (tid & 63) * 4;   // prestage hloc = Xp[t=1]
      *(float4*)&P.hloc[r * 260 + c4] =
          *(const float4*)&Xp[((size_t)BATCH + P.row0 + r) * HDIM + c4];
    }
  };
  // S1a for t=1: q from Xp[1], k from Xp[0] broadcast to all slots
  auto s1aInit = [&](Pipe& P) {
    projQ(Xp + ((size_t)BATCH + P.row0 + w) * HDIM, P.QPRE + w * HDIM + QC0);
    int col = lane >> 4, kp = lane & 15;
    const float* Wc = WKS + col * 260 + kp * 16;
    const float* Ak = Xp + (size_t)(P.row0 + w) * HDIM + kp * 16;
    float d = 0.f;
#pragma unroll
    for (int k4 = 0; k4 < 4; ++k4) {
      float4 a = *(const float4*)(Ak + 4 * k4);
      d += a.x * Wc[4 * k4] + a.y * Wc[4 * k4 + 1] + a.z * Wc[4 * k4 + 2] + a.w * Wc[4 * k4 + 3];
    }
    d += __shfl_xor(d, 1, 64); d += __shfl_xor(d, 2, 64);
    d += __shfl_xor(d, 4, 64); d += __shfl_xor(d, 8, 64);
    if (kp == 0) {
      float vk = d + bkS[col];
#pragma unroll
      for (int s = 0; s < NS; ++s) gstore(P.KPRE + (w * 8 + s) * HDIM + QC0 + col, vk);
    }
  };

  // ---- P1 phase ----
  auto p1Phase = [&](Pipe& P, int t) {
    float* MbOld = ((t - 1) & 1) ? P.MB1 : P.MB0;
    float* MbNew = (t & 1) ? P.MB1 : P.MB0;
    const float* memPrev = mem_out + (size_t)(t - 1) * BATCH * NS * HDIM;
    const float* probsPrev = probs_out + (size_t)(t - 1) * BATCH * NS;
    float* probsCur = probs_out + (size_t)t * BATCH * NS;
    // (1) q-LN (wave w = row w) -> Az0
    {
      const int hd0 = lane * 4;
      float2 v0 = gload2(P.QPRE + w * HDIM + hd0), v1 = gload2(P.QPRE + w * HDIM + hd0 + 2);
      float q[4] = {v0.x, v0.y, v1.x, v1.y};
      float s1 = q[0] + q[1] + q[2] + q[3];
      float s2 = q[0] * q[0] + q[1] * q[1] + q[2] * q[2] + q[3] * q[3];
#pragma unroll
      for (int m = 1; m < 64; m <<= 1) { s1 += __shfl_xor(s1, m, 64); s2 += __shfl_xor(s2, m, 64); }
      float mean = s1 * (1.f / 256.f);
      float inv = rsqrtf(s2 * (1.f / 256.f) - mean * mean + 1e-5f);
      *(float4*)&Az0[w * 260 + hd0] = make_float4(
          (q[0] - mean) * inv * lnqs[hd0] + lnqb[hd0],
          (q[1] - mean) * inv * lnqs[hd0 + 1] + lnqb[hd0 + 1],
          (q[2] - mean) * inv * lnqs[hd0 + 2] + lnqb[hd0 + 2],
          (q[3] - mean) * inv * lnqs[hd0 + 3] + lnqb[hd0 + 3]);
    }
    __syncthreads();
    // (2) k-LN + beta: 64 krows, 8 threads each
    {
      const int kr = tid >> 3, u8 = tid & 7, rr = kr >> 3;
      const float* kp = P.KPRE + kr * HDIM + u8 * 32;
      float kv[32]; float s1 = 0.f, s2 = 0.f;
#pragma unroll
      for (int e = 0; e < 16; ++e) {
        float2 v = gload2(kp + 2 * e);
        kv[2 * e] = v.x; kv[2 * e + 1] = v.y;
        s1 += v.x + v.y; s2 += v.x * v.x + v.y * v.y;
      }
      s1 += __shfl_xor(s1, 1, 64); s1 += __shfl_xor(s1, 2, 64); s1 += __shfl_xor(s1, 4, 64);
      s2 += __shfl_xor(s2, 1, 64); s2 += __shfl_xor(s2, 2, 64); s2 += __shfl_xor(s2, 4, 64);
      float mean = s1 * (1.f / 256.f);
      float inv = rsqrtf(s2 * (1.f / 256.f) - mean * mean + 1e-5f);
      float dot = 0.f;
#pragma unroll
      for (int e = 0; e < 32; ++e) {
        int hd = u8 * 32 + e;
        float kl = (kv[e] - mean) * inv * LNKS_[hd] + LNKB_[hd];
        float rv = fmaxf(Az0[rr * 260 + hd] + kl, 0.f);
        dot += rv * Wbs[hd];
      }
      dot += __shfl_xor(dot, 1, 64); dot += __shfl_xor(dot, 2, 64); dot += __shfl_xor(dot, 4, 64);
      if (u8 == 0) P.betaS[kr] = (dot + bbetaS[0]) * 0.0625f;
    }
    __syncthreads();
    // (3) softmax + mask + p/cp/rcp (8 threads)
    if (tid < 8) {
      int r = tid, b = P.row0 + r;
      float pp[8], pcp[8], run = 0.f;
#pragma unroll
      for (int s = 0; s < 8; s += 2) {
        float2 v = gload2(probsPrev + b * NS + s);
        pp[s] = v.x; pp[s + 1] = v.y;
      }
#pragma unroll
      for (int s = 0; s < 8; ++s) { run += pp[s]; pcp[s] = run; }
      float bmax = P.betaS[r * 8];
#pragma unroll
      for (int s = 1; s < 8; ++s) bmax = fmaxf(bmax, P.betaS[r * 8 + s]);
      float xm[8], ssum = 0.f;
#pragma unroll
      for (int s = 0; s < 8; ++s) {
        float mi = (s < 7) ? ((pcp[s + 1] < 1e-5f) ? 0.f : pcp[s + 1]) : 1.f;
        xm[s] = __expf(P.betaS[r * 8 + s] - bmax) * mi;
        ssum += fabsf(xm[s]);
      }
      float denom = fmaxf(ssum, 1e-12f);
      float run2 = 0.f, pn[8];
#pragma unroll
      for (int s = 0; s < 8; ++s) {
        pn[s] = xm[s] / denom; run2 += pn[s];
        P.cpS[r * 8 + s] = run2;
      }
      if (cg == r) {
#pragma unroll
        for (int s = 0; s < 8; s += 2) gstore2(probsCur + b * NS + s, pn[s], pn[s + 1]);
      }
      float run3 = 0.f;
#pragma unroll
      for (int s = 7; s >= 0; --s) { run3 += pn[s]; P.rcpS[r * 8 + s] = run3; }
    }
    __syncthreads();
    // (4) M-state owner update (own 4 cols, 8 rows x 8 slots)
    if (tid < 256) {
      int r = tid >> 5, s = (tid >> 2) & 7, c = tid & 3;
      int idx = (r * NS + s) * HDIM + QC0 + c;
      float rc = P.rcpS[r * 8 + s];
      float mo = gload(MbOld + idx);
      float cm = gload(memPrev + ((size_t)(P.row0 + r) * NS + s) * HDIM + QC0 + c);
      gstore(MbNew + idx, mo * (1.f - rc) + cm * rc);
    }
    // (5) stage Ast = blend(MbOld, memPrev) slot0 (hloc was prestaged)
    {
      const int r = tid >> 6, c4 = (tid & 63) * 4;
      float rc0 = P.rcpS[r * 8];
      float2 m0 = gload2(MbOld + (r * NS) * HDIM + c4);
      float2 m1 = gload2(MbOld + (r * NS) * HDIM + c4 + 2);
      float2 c0 = gload2(memPrev + ((size_t)(P.row0 + r) * NS) * HDIM + c4);
      float2 c1 = gload2(memPrev + ((size_t)(P.row0 + r) * NS) * HDIM + c4 + 2);
      *(float4*)&P.Ast[r * 260 + c4] = make_float4(
          m0.x * (1.f - rc0) + c0.x * rc0, m0.y * (1.f - rc0) + c0.y * rc0,
          m1.x * (1.f - rc0) + c1.x * rc0, m1.y * (1.f - rc0) + c1.y * rc0);
    }
    __syncthreads();
    // Z1(0)
    {
      float a00 = 0.f, a01 = 0.f;
      z1Half(P.Ast, 256, a00, a01);
      z1Half(P.hloc, 0, a00, a01);
      redFinish(a00, a01, P.Z1c, b1s, true);
    }
  };

  // ---- cell section 1: Z2(ci) ----
  auto cellS1 = [&](Pipe& P, int phRdy) {
    waitF(P.flags, phRdy);
    const int r = tid >> 6, c4 = (tid & 63) * 4;
    const float* zr = P.Z1c + r * H4 + c4;
    float2 pf[8];
#pragma unroll
    for (int ch = 0; ch < 4; ++ch) {
      pf[ch * 2] = gload2(zr + ch * 256);
      pf[ch * 2 + 1] = gload2(zr + ch * 256 + 2);
    }
    *(float4*)&Az0[r * 260 + c4] = make_float4(pf[0].x, pf[0].y, pf[1].x, pf[1].y);
    __syncthreads();
    float za0 = 0.f, za1 = 0.f;
#pragma unroll
    for (int ch = 0; ch < 4; ++ch) {
      const float* buf = (ch & 1) ? Az1 : Az0;
      float* nbuf = (ch & 1) ? Az0 : Az1;
      const int kb = w * 32, kw0 = ch * 256 + kb;
#pragma unroll
      for (int kk = 0; kk < 32; kk += 8) {
        float4 x0 = *(const float4*)&buf[rl * 260 + kb + kk];
        float4 x1 = *(const float4*)&buf[rl * 260 + kb + kk + 4];
        uint4 u0 = *(const uint4*)&W2b[cl * 1032 + kw0 + kk];
        uint4 u1 = *(const uint4*)&W2b[(cl + 8) * 1032 + kw0 + kk];
        fma8(za0, x0, x1, u0); fma8(za1, x0, x1, u1);
      }
      if (ch < 3)
        *(float4*)&nbuf[r * 260 + c4] =
            make_float4(pf[ch * 2 + 2].x, pf[ch * 2 + 2].y, pf[ch * 2 + 3].x, pf[ch * 2 + 3].y);
      __syncthreads();
    }
    redFinish(za0, za1, P.Z2c, b2s, false);
  };

  // ---- cell section 2: window + H(ci) + Z1(ci+1) ----
  auto cellS2 = [&](Pipe& P, int ci, int t, int phA, float* memCur) {
    const bool lastT = (t == T_LEN - 1);
    // hiv (Ast slot ci, row w) before restage
    float4 hv = *(const float4*)&P.Ast[w * 260 + lane * 4];
    __syncthreads();
    if (ci < 7) {
      float* MbNew = (t & 1) ? P.MB1 : P.MB0;
      const int r = tid >> 6, c4 = (tid & 63) * 4;
      float2 a = gload2(MbNew + (r * NS + ci + 1) * HDIM + c4);
      float2 b = gload2(MbNew + (r * NS + ci + 1) * HDIM + c4 + 2);
      *(float4*)&P.Ast[r * 260 + c4] = make_float4(a.x, a.y, b.x, b.y);
    } else if (!lastT) {
      // KPRE(s=6) from memCur slot 6 (visible: waited sigB(6) in S1(7))
      projK_G(memCur + ((size_t)(P.row0 + w) * NS + 6) * HDIM,
              P.KPRE + (w * 8 + 6) * HDIM + QC0);
    }
    __syncthreads();
    float b00 = 0.f, b01 = 0.f;
    if (ci < 7) z1Half(P.Ast, 256, b00, b01);   // Mn-half of Z1(ci+1)
    waitF(P.flags, phA);
    // ---- H: wave w = row w, 4 h-dims per lane ----
    {
      const float* z2r = P.Z2c + w * H4;
      const int hd0 = lane * 4;
      float2 cv0 = gload2(z2r + 768 + hd0), cv1 = gload2(z2r + 768 + hd0 + 2);
      float cc[4] = {cv0.x, cv0.y, cv1.x, cv1.y};
      float s1 = cc[0] + cc[1] + cc[2] + cc[3];
      float s2 = cc[0] * cc[0] + cc[1] * cc[1] + cc[2] * cc[2] + cc[3] * cc[3];
#pragma unroll
      for (int m = 1; m < 64; m <<= 1) { s1 += __shfl_xor(s1, m, 64); s2 += __shfl_xor(s2, m, 64); }
      float mean = s1 * (1.f / 256.f);
      float inv = rsqrtf(s2 * (1.f / 256.f) - mean * mean + 1e-5f);
      float g[12];
#pragma unroll
      for (int j = 0; j < 6; ++j) {
        float2 v = gload2(z2r + hd0 * 3 + 2 * j);
        g[2 * j] = v.x; g[2 * j + 1] = v.y;
      }
      float4 vi4 = *(const float4*)&P.hloc[w * 260 + hd0];
      float4 xp4 = *(const float4*)&Xp[((size_t)t * BATCH + P.row0 + w) * HDIM + hd0];
      float viv[4] = {vi4.x, vi4.y, vi4.z, vi4.w};
      float xpv[4] = {xp4.x, xp4.y, xp4.z, xp4.w};
      float hivv[4] = {hv.x, hv.y, hv.z, hv.w};
      float cp = P.cpS[w * 8 + ci];
      float hn[4];
#pragma unroll
      for (int j = 0; j < 4; ++j) {
        int hd = hd0 + j;
        float z0 = g[3 * j], z1v = g[3 * j + 1], z2g = g[3 * j + 2];
        float gm = fmaxf(z0, fmaxf(z1v, z2g));
        float e0 = __expf(z0 - gm), e1 = __expf(z1v - gm), e2 = __expf(z2g - gm);
        float act = ftanh((cc[j] - mean) * inv * LNS_[hd] + LNB_[hd]);
        float hc = (e0 * viv[j] + e1 * hivv[j] + e2 * act) * __builtin_amdgcn_rcpf(e0 + e1 + e2);
        hn[j] = xpv[j] * (1.f - cp) + hc * cp;
      }
      *(float4*)&P.hloc[w * 260 + hd0] = make_float4(hn[0], hn[1], hn[2], hn[3]);
      if (lane == cg) {   // lane*4 == QC0: owner writes 4 cols
        float* mp = memCur + ((size_t)(P.row0 + w) * NS + ci) * HDIM + QC0;
        gstore2(mp, hn[0], hn[1]);
        gstore2(mp + 2, hn[2], hn[3]);
      }
    }
    __syncthreads();
    if (ci < 7) {
      z1Half(P.hloc, 0, b00, b01);   // h-half of Z1(ci+1)
      redFinish(b00, b01, P.Z1c, b1s, true);
    } else if (!lastT) {
      // KPRE(s=7) from new h (LDS) — pre-sigB
      projK_L(&P.hloc[w * 260], P.KPRE + (w * 8 + 7) * HDIM + QC0);
    }
  };

  // ---- B-window: S1a(t+1) pieces, drained by NEXT signal ----
  auto bWin = [&](Pipe& P, int ci, int t, float* memCur) {
    if (ci == 0) {
      projQ(Xp + ((size_t)(t + 1) * BATCH + P.row0 + w) * HDIM, P.QPRE + w * HDIM + QC0);
    } else if (ci <= 6) {
      const int s = ci - 1;   // memCur slot s visible (waited sigB(s) in S1(ci))
      projK_G(memCur + ((size_t)(P.row0 + w) * NS + s) * HDIM,
              P.KPRE + (w * 8 + s) * HDIM + QC0);
    } else {
      const int r = tid >> 6, c4 = (tid & 63) * 4;   // prestage hloc = Xp[t+1]
      *(float4*)&P.hloc[r * 260 + c4] =
          *(const float4*)&Xp[((size_t)(t + 1) * BATCH + P.row0 + r) * HDIM + c4];
    }
  };

  // ================= init + time loop =================
  __syncthreads();
  initPipe(P0); initPipe(P1);
  __syncthreads();
  s1aInit(P0); s1aInit(P1);
  int ph = 1;
  sigBoth(ph);
  waitF(P0.flags, ph); waitF(P1.flags, ph);

  for (int t = 1; t < T_LEN; ++t) {
    const bool lastT = (t == T_LEN - 1);
    float* memCur = mem_out + (size_t)t * BATCH * NS * HDIM;
    p1Phase(P0, t);
    p1Phase(P1, t);
    ++ph; sigBoth(ph);
    for (int ci = 0; ci < NS; ++ci) {
      const int phRdy = ph;
      cellS1(P0, phRdy);
      cellS1(P1, phRdy);
      ++ph; sigBoth(ph);
      cellS2(P0, ci, t, ph, memCur);
      cellS2(P1, ci, t, ph, memCur);
      ++ph; sigBoth(ph);
      if (!lastT) { bWin(P0, ci, t, memCur); bWin(P1, ci, t, memCur); }
    }
    waitF(P0.flags, ph); waitF(P1.flags, ph);
  }
}

extern "C" void kernel_launch(void* const* d_in, const int* in_sizes, int n_in,
                              void* d_out, int out_size, void* d_ws, size_t ws_size,
                              hipStream_t stream) {
  (void)in_sizes; (void)n_in; (void)out_size; (void)ws_size;
  const float* X     = (const float*)d_in[0];
  const float* Wp    = (const float*)d_in[3];
  const float* bp    = (const float*)d_in[4];
  const float* lns   = (const float*)d_in[5];
  const float* lnb   = (const float*)d_in[6];
  const float* Wq    = (const float*)d_in[7];
  const float* bq    = (const float*)d_in[8];
  const float* lnqs  = (const float*)d_in[9];
  const float* lnqb  = (const float*)d_in[10];
  const float* Wk    = (const float*)d_in[11];
  const float* bk    = (const float*)d_in[12];
  const float* lnks  = (const float*)d_in[13];
  const float* lnkb  = (const float*)d_in[14];
  const float* Wbeta = (const float*)d_in[15];
  const float* bbeta = (const float*)d_in[16];
  const float* W1    = (const float*)d_in[17];
  const float* b1    = (const float*)d_in[18];
  const float* W2    = (const float*)d_in[19];
  const float* b2    = (const float*)d_in[20];

  float* out       = (float*)d_out;
  float* out_xp    = out;
  float* out_mem   = out + (size_t)T_LEN * BATCH * HDIM;
  float* out_probs = out_mem + (size_t)T_LEN * BATCH * NS * HDIM;
  float* ws        = (float*)d_ws;

  hipLaunchKernelGGL(init_ctrl, dim3(4), dim3(256), 0, stream, (int*)d_ws);
  hipLaunchKernelGGL(xp_kernel, dim3(1024), dim3(256), 0, stream, X, Wp, bp, lns, lnb, out_xp);
  hipLaunchKernelGGL(omr_main, dim3(256), dim3(NTHR), 0, stream,
                     out_xp, Wq, bq, lnqs, lnqb, Wk, bk, lnks, lnkb, Wbeta, bbeta,
                     W1, b1, W2, b2, lns, lnb, out_mem, out_probs, ws);
}

// Round 5
// 17934.749 us; speedup vs baseline: 1.2404x; 1.0883x over previous
//
#include <hip/hip_runtime.h>
#include <hip/hip_bf16.h>
#include <math.h>

#define T_LEN 128
#define BATCH 64
#define IND   512
#define HDIM  256
#define NS    8
#define H4    1024
#define NTHR  512
#define RPC   8        // rows per cluster (pipeline)
#define CSTRIDE 67584  // floats per cluster in ws

typedef unsigned long long ull;
typedef unsigned int uint;
typedef unsigned short ushort;

// ---- LLC-coherent accessors (bypass per-XCD L2): agent-scope relaxed atomics ----
__device__ __forceinline__ float gload(const float* p) {
  return __hip_atomic_load(p, __ATOMIC_RELAXED, __HIP_MEMORY_SCOPE_AGENT);
}
__device__ __forceinline__ float2 gload2(const float* p) {
  ull v = __hip_atomic_load((const ull*)p, __ATOMIC_RELAXED, __HIP_MEMORY_SCOPE_AGENT);
  return __builtin_bit_cast(float2, v);
}
__device__ __forceinline__ void gstore(float* p, float v) {
  __hip_atomic_store(p, v, __ATOMIC_RELAXED, __HIP_MEMORY_SCOPE_AGENT);
}
__device__ __forceinline__ void gstore2(float* p, float a, float b) {
  float2 t = make_float2(a, b);
  __hip_atomic_store((ull*)p, __builtin_bit_cast(ull, t), __ATOMIC_RELAXED, __HIP_MEMORY_SCOPE_AGENT);
}

__device__ __forceinline__ float2 bf2(uint u) {
  return make_float2(__uint_as_float(u << 16), __uint_as_float(u & 0xffff0000u));
}
// 8 bf16 weights vs 8 fp32 A values -> acc
__device__ __forceinline__ void fma8(float& acc, float4 x0, float4 x1, uint4 u) {
  float2 wA = bf2(u.x), wB = bf2(u.y), wC = bf2(u.z), wD = bf2(u.w);
  acc += x0.x * wA.x + x0.y * wA.y + x0.z * wB.x + x0.w * wB.y
       + x1.x * wC.x + x1.y * wC.y + x1.z * wD.x + x1.w * wD.y;
}

// fast tanh via hw exp
__device__ __forceinline__ float ftanh(float x) {
  float xc = fminf(fmaxf(x, -9.f), 9.f);
  float t = __expf(2.f * xc);
  return (t - 1.f) * __builtin_amdgcn_rcpf(t + 1.f);
}

extern "C" __global__ void init_ctrl(int* ctrl) {
  int t = blockIdx.x * blockDim.x + threadIdx.x;
  if (t < 1024) ctrl[t] = 0;
}

// ---------------- Xp = tanh(LN(X @ W_proj + b)) ----------------
extern "C" __global__ __launch_bounds__(256) void xp_kernel(
    const float* __restrict__ X, const float* __restrict__ Wp, const float* __restrict__ bp,
    const float* __restrict__ lns, const float* __restrict__ lnb, float* __restrict__ out_xp)
{
  __shared__ float Xs[8 * IND];
  __shared__ float Ys[8 * HDIM];
  const int tid = threadIdx.x;
  const size_t base = (size_t)blockIdx.x * 8;
  const float* Xb = X + base * IND;
  for (int e = tid; e < 8 * IND / 4; e += 256) ((float4*)Xs)[e] = ((const float4*)Xb)[e];
  __syncthreads();
  float acc[8];
#pragma unroll
  for (int r = 0; r < 8; ++r) acc[r] = 0.f;
  for (int k = 0; k < IND; ++k) {
    float wv = Wp[k * HDIM + tid];
#pragma unroll
    for (int r = 0; r < 8; ++r) acc[r] += Xs[r * IND + k] * wv;
  }
  float bpv = bp[tid];
#pragma unroll
  for (int r = 0; r < 8; ++r) Ys[r * HDIM + tid] = acc[r] + bpv;
  __syncthreads();
  int w = tid >> 6, lane = tid & 63;
  for (int rr = 0; rr < 2; ++rr) {
    int r = w * 2 + rr;
    float v[4]; float s1 = 0.f, s2 = 0.f;
#pragma unroll
    for (int e = 0; e < 4; ++e) { v[e] = Ys[r * HDIM + lane + 64 * e]; s1 += v[e]; s2 += v[e] * v[e]; }
#pragma unroll
    for (int off = 32; off > 0; off >>= 1) { s1 += __shfl_xor(s1, off, 64); s2 += __shfl_xor(s2, off, 64); }
    float m = s1 / 256.f;
    float iv = rsqrtf(s2 / 256.f - m * m + 1e-5f);
#pragma unroll
    for (int e = 0; e < 4; ++e) {
      int hd = lane + 64 * e;
      out_xp[(base + r) * HDIM + hd] = tanhf((v[e] - m) * iv * lns[hd] + lnb[hd]);
    }
  }
}

// ws float layout: [0..1023] int flags (cluster cl: ints [cl*64, cl*64+64)), 8 clusters;
// data base = 1024; per cluster cl (8 clusters of 8 rows), stride 67584:
//   QPRE +0 (2048), KPRE +2048 (16384), MB0 +18432 (16384), MB1 +34816 (16384),
//   Z1c +51200 (8192), Z2c +59392 (8192)

struct Pipe {
  float *QPRE, *KPRE, *MB0, *MB1, *Z1c, *Z2c;
  int* flags;
  float *hloc, *Ast, *cpS, *rcpS, *betaS;
  int row0;
};

// ---------------- main recurrent kernel: 8 clusters, 2 pipelines per block ----------------
extern "C" __global__ __launch_bounds__(NTHR, 1) void omr_main(
    const float* __restrict__ Xp,
    const float* __restrict__ Wq, const float* __restrict__ bq,
    const float* __restrict__ lnqs, const float* __restrict__ lnqb,
    const float* __restrict__ Wk, const float* __restrict__ bk,
    const float* __restrict__ lnks, const float* __restrict__ lnkb,
    const float* __restrict__ Wbeta, const float* __restrict__ bbeta,
    const float* __restrict__ W1, const float* __restrict__ b1,
    const float* __restrict__ W2, const float* __restrict__ b2,
    const float* __restrict__ lns, const float* __restrict__ lnb,
    float* __restrict__ mem_out, float* __restrict__ probs_out, float* __restrict__ ws)
{
  const int tid = threadIdx.x;
  const int sc = blockIdx.x >> 6;   // supercluster (4), pipes = clusters 2sc, 2sc+1
  const int cg = blockIdx.x & 63;   // column group within supercluster
  const int ZC0 = cg * 16;          // z1/z2 cols owned
  const int QC0 = cg * 4;           // q/k/h cols owned
  const int w = tid >> 6, lane = tid & 63;
  const int rl = lane >> 3, cl = lane & 7;   // 8x8 lane grid: rows (rl, rl+8), cols (cl, cl+8)

  // LDS ~137 KB; GEMM strides ≡ 4 mod 32 banks
  __shared__ ushort W1b[16 * 520];    // bf16 W1 col slice (shared by both pipes)
  __shared__ ushort W2b[16 * 1032];   // bf16 W2 col slice
  __shared__ float hloc0[RPC * 260], hloc1[RPC * 260];
  __shared__ float Ast0[RPC * 260], Ast1[RPC * 260];
  __shared__ float Az0[16 * 260], Az1[16 * 260];   // merged 16-row staging (dbuf)
  __shared__ float redS[8 * 260];                  // split-K partials (16x16 tile)
  __shared__ float LNS_[256], LNB_[256], LNKS_[256], LNKB_[256], Wbs[256];
  __shared__ float WQS[4 * 260], WKS[4 * 260];
  __shared__ float cp0[64], cp1[64], rcp0[64], rcp1[64], bet0[64], bet1[64];
  __shared__ float b1s[16], b2s[16], bqS[4], bkS[4], bbetaS[1];

  auto mkPipe = [&](int p, float* hl, float* as, float* cp, float* rcp, float* bet) {
    Pipe P;
    int clid = sc * 2 + p;
    float* base = ws + 1024 + (size_t)clid * CSTRIDE;
    P.QPRE = base; P.KPRE = base + 2048;
    P.MB0 = base + 18432; P.MB1 = base + 34816;
    P.Z1c = base + 51200; P.Z2c = base + 59392;
    P.flags = (int*)ws + clid * 64;
    P.hloc = hl; P.Ast = as; P.cpS = cp; P.rcpS = rcp; P.betaS = bet;
    P.row0 = clid * RPC;
    return P;
  };
  Pipe P0 = mkPipe(0, hloc0, Ast0, cp0, rcp0, bet0);
  Pipe P1 = mkPipe(1, hloc1, Ast1, cp1, rcp1, bet1);

  // ---- resident weights / params ----
  for (int e = tid; e < 16 * 512; e += NTHR) {
    int k = e >> 4, c = e & 15;
    __hip_bfloat16 h = __float2bfloat16(W1[(size_t)k * H4 + ZC0 + c]);
    W1b[c * 520 + k] = *reinterpret_cast<ushort*>(&h);
  }
  for (int e = tid; e < 16 * 1024; e += NTHR) {
    int k = e >> 4, c = e & 15;
    __hip_bfloat16 h = __float2bfloat16(W2[(size_t)k * H4 + ZC0 + c]);
    W2b[c * 1032 + k] = *reinterpret_cast<ushort*>(&h);
  }
  for (int e = tid; e < 2048; e += NTHR) {
    int s = e >> 10, c = (e >> 8) & 3, k = e & 255;
    (s ? WKS : WQS)[c * 260 + k] = (s ? Wk : Wq)[k * HDIM + QC0 + c];
  }
  if (tid < 256) {
    LNS_[tid] = lns[tid];  LNB_[tid] = lnb[tid];
    LNKS_[tid] = lnks[tid]; LNKB_[tid] = lnkb[tid];
    Wbs[tid] = Wbeta[tid];
  }
  if (tid < 16) { b1s[tid] = b1[ZC0 + tid]; b2s[tid] = b2[ZC0 + tid]; }
  if (tid < 4)  { bqS[tid] = bq[QC0 + tid]; bkS[tid] = bk[QC0 + tid]; }
  if (tid == 0) bbetaS[0] = bbeta[0];

  // ---- barrier primitives ----
  auto waitBoth = [&](int p) {
    if (tid < 64) {
      while (__hip_atomic_load(P0.flags + tid, __ATOMIC_RELAXED, __HIP_MEMORY_SCOPE_AGENT) < p) {}
    } else if (tid < 128) {
      while (__hip_atomic_load(P1.flags + (tid - 64), __ATOMIC_RELAXED, __HIP_MEMORY_SCOPE_AGENT) < p) {}
    }
    __syncthreads();
  };
  auto sigBoth = [&](int p) {
    asm volatile("s_waitcnt vmcnt(0)" ::: "memory");
    __syncthreads();
    if (tid == 0) __hip_atomic_store(P0.flags + cg, p, __ATOMIC_RELAXED, __HIP_MEMORY_SCOPE_AGENT);
    if (tid == 1) __hip_atomic_store(P1.flags + cg, p, __ATOMIC_RELAXED, __HIP_MEMORY_SCOPE_AGENT);
  };

  // ---- merged 16-row Z1 GEMM half: rows 0-7 from A0 (pipe0), 8-15 from A1 ----
  auto z1HalfM = [&](const float* A0, const float* A1, int kwBase,
                     float& a00, float& a01, float& a10, float& a11) {
    const int kb = w * 32;
#pragma unroll
    for (int kk = 0; kk < 32; kk += 8) {
      const int ka = kb + kk, kw = kwBase + kb + kk;
      float4 x0 = *(const float4*)&A0[rl * 260 + ka];
      float4 x1 = *(const float4*)&A0[rl * 260 + ka + 4];
      float4 y0 = *(const float4*)&A1[rl * 260 + ka];
      float4 y1 = *(const float4*)&A1[rl * 260 + ka + 4];
      uint4 u0 = *(const uint4*)&W1b[cl * 520 + kw];
      uint4 u1 = *(const uint4*)&W1b[(cl + 8) * 520 + kw];
      fma8(a00, x0, x1, u0); fma8(a01, x0, x1, u1);
      fma8(a10, y0, y1, u0); fma8(a11, y0, y1, u1);
    }
  };
  // merged reduce+store: rows 0-7 -> dst0, 8-15 -> dst1
  auto redFinishM = [&](float a00, float a01, float a10, float a11,
                        float* dst0, float* dst1, const float* bias, bool doRelu) {
    __syncthreads();                    // protect prior redS readers
    redS[w * 260 + rl * 16 + cl] = a00;
    redS[w * 260 + rl * 16 + cl + 8] = a01;
    redS[w * 260 + (rl + 8) * 16 + cl] = a10;
    redS[w * 260 + (rl + 8) * 16 + cl + 8] = a11;
    __syncthreads();
    if (tid < 128) {
      int r = tid >> 3, c0 = (tid & 7) * 2;
      float v0 = 0.f, v1 = 0.f;
#pragma unroll
      for (int w2 = 0; w2 < 8; ++w2) {
        v0 += redS[w2 * 260 + r * 16 + c0];
        v1 += redS[w2 * 260 + r * 16 + c0 + 1];
      }
      v0 += bias[c0]; v1 += bias[c0 + 1];
      if (doRelu) { v0 = fmaxf(v0, 0.f); v1 = fmaxf(v1, 0.f); }
      float* dst = (r < 8) ? dst0 : dst1;
      gstore2(dst + (r & 7) * H4 + ZC0 + c0, v0, v1);
    }
  };

  // ---- 4-col projections (wave w = row w; 16 lanes per col) ----
  auto projQ = [&](const float* A /*plain global row*/, float* dst) {
    int col = lane >> 4, kp = lane & 15;
    const float* Wc = WQS + col * 260 + kp * 16;
    const float* Ak = A + kp * 16;
    float d = 0.f;
#pragma unroll
    for (int k4 = 0; k4 < 4; ++k4) {
      float4 a = *(const float4*)(Ak + 4 * k4);
      d += a.x * Wc[4 * k4] + a.y * Wc[4 * k4 + 1] + a.z * Wc[4 * k4 + 2] + a.w * Wc[4 * k4 + 3];
    }
    d += __shfl_xor(d, 1, 64); d += __shfl_xor(d, 2, 64);
    d += __shfl_xor(d, 4, 64); d += __shfl_xor(d, 8, 64);
    if (kp == 0) gstore(dst + col, d + bqS[col]);
  };
  auto projK_G = [&](const float* A /*LLC row (gload)*/, float* dst) {
    int col = lane >> 4, kp = lane & 15;
    const float* Wc = WKS + col * 260 + kp * 16;
    const float* Ak = A + kp * 16;
    float d = 0.f;
#pragma unroll
    for (int k2 = 0; k2 < 8; ++k2) {
      float2 a = gload2(Ak + 2 * k2);
      d += a.x * Wc[2 * k2] + a.y * Wc[2 * k2 + 1];
    }
    d += __shfl_xor(d, 1, 64); d += __shfl_xor(d, 2, 64);
    d += __shfl_xor(d, 4, 64); d += __shfl_xor(d, 8, 64);
    if (kp == 0) gstore(dst + col, d + bkS[col]);
  };
  auto projK_L = [&](const float* A /*LDS row*/, float* dst) {
    int col = lane >> 4, kp = lane & 15;
    const float* Wc = WKS + col * 260 + kp * 16;
    const float* Ak = A + kp * 16;
    float d = 0.f;
#pragma unroll
    for (int k4 = 0; k4 < 4; ++k4) {
      float4 a = *(const float4*)(Ak + 4 * k4);
      d += a.x * Wc[4 * k4] + a.y * Wc[4 * k4 + 1] + a.z * Wc[4 * k4 + 2] + a.w * Wc[4 * k4 + 3];
    }
    d += __shfl_xor(d, 1, 64); d += __shfl_xor(d, 2, 64);
    d += __shfl_xor(d, 4, 64); d += __shfl_xor(d, 8, 64);
    if (kp == 0) gstore(dst + col, d + bkS[col]);
  };

  // ---- t=0 init per pipe ----
  auto initPipe = [&](Pipe& P) {
    if (tid < 256) {
      int e = cg * 256 + tid;          // 16384 floats over 64 blocks
      gstore(P.MB0 + e, 0.f);
      int r = e >> 11, s = (e >> 8) & 7, hd = e & 255;
      gstore(mem_out + ((size_t)(P.row0 + r) * NS + s) * HDIM + hd,
             Xp[(size_t)(P.row0 + r) * HDIM + hd]);
    }
    if (cg == 0 && tid < 64) gstore(probs_out + P.row0 * NS + tid, 0.f);
    {
      int r = tid >> 6, c4 = (tid & 63) * 4;   // prestage hloc = Xp[t=1]
      *(float4*)&P.hloc[r * 260 + c4] =
          *(const float4*)&Xp[((size_t)BATCH + P.row0 + r) * HDIM + c4];
    }
  };
  // S1a for t=1: q from Xp[1], k from Xp[0] broadcast to all slots
  auto s1aInit = [&](Pipe& P) {
    projQ(Xp + ((size_t)BATCH + P.row0 + w) * HDIM, P.QPRE + w * HDIM + QC0);
    int col = lane >> 4, kp = lane & 15;
    const float* Wc = WKS + col * 260 + kp * 16;
    const float* Ak = Xp + (size_t)(P.row0 + w) * HDIM + kp * 16;
    float d = 0.f;
#pragma unroll
    for (int k4 = 0; k4 < 4; ++k4) {
      float4 a = *(const float4*)(Ak + 4 * k4);
      d += a.x * Wc[4 * k4] + a.y * Wc[4 * k4 + 1] + a.z * Wc[4 * k4 + 2] + a.w * Wc[4 * k4 + 3];
    }
    d += __shfl_xor(d, 1, 64); d += __shfl_xor(d, 2, 64);
    d += __shfl_xor(d, 4, 64); d += __shfl_xor(d, 8, 64);
    if (kp == 0) {
      float vk = d + bkS[col];
#pragma unroll
      for (int s = 0; s < NS; ++s) gstore(P.KPRE + (w * 8 + s) * HDIM + QC0 + col, vk);
    }
  };

  // ---- P1 core (per pipe): LN/softmax/M-update/Ast-stage; GEMM merged outside ----
  auto p1Core = [&](Pipe& P, int t) {
    float* MbOld = ((t - 1) & 1) ? P.MB1 : P.MB0;
    float* MbNew = (t & 1) ? P.MB1 : P.MB0;
    const float* memPrev = mem_out + (size_t)(t - 1) * BATCH * NS * HDIM;
    const float* probsPrev = probs_out + (size_t)(t - 1) * BATCH * NS;
    float* probsCur = probs_out + (size_t)t * BATCH * NS;
    // (1) q-LN (wave w = row w) -> Az0 rows 0..7
    {
      const int hd0 = lane * 4;
      float2 v0 = gload2(P.QPRE + w * HDIM + hd0), v1 = gload2(P.QPRE + w * HDIM + hd0 + 2);
      float q[4] = {v0.x, v0.y, v1.x, v1.y};
      float s1 = q[0] + q[1] + q[2] + q[3];
      float s2 = q[0] * q[0] + q[1] * q[1] + q[2] * q[2] + q[3] * q[3];
#pragma unroll
      for (int m = 1; m < 64; m <<= 1) { s1 += __shfl_xor(s1, m, 64); s2 += __shfl_xor(s2, m, 64); }
      float mean = s1 * (1.f / 256.f);
      float inv = rsqrtf(s2 * (1.f / 256.f) - mean * mean + 1e-5f);
      *(float4*)&Az0[w * 260 + hd0] = make_float4(
          (q[0] - mean) * inv * lnqs[hd0] + lnqb[hd0],
          (q[1] - mean) * inv * lnqs[hd0 + 1] + lnqb[hd0 + 1],
          (q[2] - mean) * inv * lnqs[hd0 + 2] + lnqb[hd0 + 2],
          (q[3] - mean) * inv * lnqs[hd0 + 3] + lnqb[hd0 + 3]);
    }
    __syncthreads();
    // (2) k-LN + beta: 64 krows, 8 threads each
    {
      const int kr = tid >> 3, u8 = tid & 7, rr = kr >> 3;
      const float* kp = P.KPRE + kr * HDIM + u8 * 32;
      float kv[32]; float s1 = 0.f, s2 = 0.f;
#pragma unroll
      for (int e = 0; e < 16; ++e) {
        float2 v = gload2(kp + 2 * e);
        kv[2 * e] = v.x; kv[2 * e + 1] = v.y;
        s1 += v.x + v.y; s2 += v.x * v.x + v.y * v.y;
      }
      s1 += __shfl_xor(s1, 1, 64); s1 += __shfl_xor(s1, 2, 64); s1 += __shfl_xor(s1, 4, 64);
      s2 += __shfl_xor(s2, 1, 64); s2 += __shfl_xor(s2, 2, 64); s2 += __shfl_xor(s2, 4, 64);
      float mean = s1 * (1.f / 256.f);
      float inv = rsqrtf(s2 * (1.f / 256.f) - mean * mean + 1e-5f);
      float dot = 0.f;
#pragma unroll
      for (int e = 0; e < 32; ++e) {
        int hd = u8 * 32 + e;
        float kl = (kv[e] - mean) * inv * LNKS_[hd] + LNKB_[hd];
        float rv = fmaxf(Az0[rr * 260 + hd] + kl, 0.f);
        dot += rv * Wbs[hd];
      }
      dot += __shfl_xor(dot, 1, 64); dot += __shfl_xor(dot, 2, 64); dot += __shfl_xor(dot, 4, 64);
      if (u8 == 0) P.betaS[kr] = (dot + bbetaS[0]) * 0.0625f;
    }
    __syncthreads();
    // (3) softmax + mask + p/cp/rcp (8 threads)
    if (tid < 8) {
      int r = tid, b = P.row0 + r;
      float pp[8], pcp[8], run = 0.f;
#pragma unroll
      for (int s = 0; s < 8; s += 2) {
        float2 v = gload2(probsPrev + b * NS + s);
        pp[s] = v.x; pp[s + 1] = v.y;
      }
#pragma unroll
      for (int s = 0; s < 8; ++s) { run += pp[s]; pcp[s] = run; }
      float bmax = P.betaS[r * 8];
#pragma unroll
      for (int s = 1; s < 8; ++s) bmax = fmaxf(bmax, P.betaS[r * 8 + s]);
      float xm[8], ssum = 0.f;
#pragma unroll
      for (int s = 0; s < 8; ++s) {
        float mi = (s < 7) ? ((pcp[s + 1] < 1e-5f) ? 0.f : pcp[s + 1]) : 1.f;
        xm[s] = __expf(P.betaS[r * 8 + s] - bmax) * mi;
        ssum += fabsf(xm[s]);
      }
      float denom = fmaxf(ssum, 1e-12f);
      float run2 = 0.f, pn[8];
#pragma unroll
      for (int s = 0; s < 8; ++s) {
        pn[s] = xm[s] / denom; run2 += pn[s];
        P.cpS[r * 8 + s] = run2;
      }
      if (cg == r) {
#pragma unroll
        for (int s = 0; s < 8; s += 2) gstore2(probsCur + b * NS + s, pn[s], pn[s + 1]);
      }
      float run3 = 0.f;
#pragma unroll
      for (int s = 7; s >= 0; --s) { run3 += pn[s]; P.rcpS[r * 8 + s] = run3; }
    }
    __syncthreads();
    // (4) M-state owner update (own 4 cols, 8 rows x 8 slots)
    if (tid < 256) {
      int r = tid >> 5, s = (tid >> 2) & 7, c = tid & 3;
      int idx = (r * NS + s) * HDIM + QC0 + c;
      float rc = P.rcpS[r * 8 + s];
      float mo = gload(MbOld + idx);
      float cm = gload(memPrev + ((size_t)(P.row0 + r) * NS + s) * HDIM + QC0 + c);
      gstore(MbNew + idx, mo * (1.f - rc) + cm * rc);
    }
    // (5) stage Ast = blend(MbOld, memPrev) slot0 (hloc was prestaged)
    {
      const int r = tid >> 6, c4 = (tid & 63) * 4;
      float rc0 = P.rcpS[r * 8];
      float2 m0 = gload2(MbOld + (r * NS) * HDIM + c4);
      float2 m1 = gload2(MbOld + (r * NS) * HDIM + c4 + 2);
      float2 c0 = gload2(memPrev + ((size_t)(P.row0 + r) * NS) * HDIM + c4);
      float2 c1 = gload2(memPrev + ((size_t)(P.row0 + r) * NS) * HDIM + c4 + 2);
      *(float4*)&P.Ast[r * 260 + c4] = make_float4(
          m0.x * (1.f - rc0) + c0.x * rc0, m0.y * (1.f - rc0) + c0.y * rc0,
          m1.x * (1.f - rc0) + c1.x * rc0, m1.y * (1.f - rc0) + c1.y * rc0);
    }
    __syncthreads();
  };

  // ---- cell section 1: merged Z2(ci) for both pipes ----
  auto cellS1M = [&](int phRdy) {
    waitBoth(phRdy);
    // gather both pipes' z1 rows: thread -> row r16 (0..15), 8 cols at c8
    const int r16 = tid >> 5, c8 = (tid & 31) * 8;
    const float* zr = ((r16 < 8) ? P0.Z1c : P1.Z1c) + (r16 & 7) * H4 + c8;
    float2 pf[16];
#pragma unroll
    for (int ch = 0; ch < 4; ++ch) {
      const float* zq = zr + ch * 256;
      pf[ch * 4 + 0] = gload2(zq);     pf[ch * 4 + 1] = gload2(zq + 2);
      pf[ch * 4 + 2] = gload2(zq + 4); pf[ch * 4 + 3] = gload2(zq + 6);
    }
    *(float4*)&Az0[r16 * 260 + c8] = make_float4(pf[0].x, pf[0].y, pf[1].x, pf[1].y);
    *(float4*)&Az0[r16 * 260 + c8 + 4] = make_float4(pf[2].x, pf[2].y, pf[3].x, pf[3].y);
    __syncthreads();
    float za00 = 0.f, za01 = 0.f, za10 = 0.f, za11 = 0.f;
#pragma unroll
    for (int ch = 0; ch < 4; ++ch) {
      const float* buf = (ch & 1) ? Az1 : Az0;
      float* nbuf = (ch & 1) ? Az0 : Az1;
      const int kb = w * 32, kw0 = ch * 256 + kb;
#pragma unroll
      for (int kk = 0; kk < 32; kk += 8) {
        float4 x0 = *(const float4*)&buf[rl * 260 + kb + kk];
        float4 x1 = *(const float4*)&buf[rl * 260 + kb + kk + 4];
        float4 y0 = *(const float4*)&buf[(rl + 8) * 260 + kb + kk];
        float4 y1 = *(const float4*)&buf[(rl + 8) * 260 + kb + kk + 4];
        uint4 u0 = *(const uint4*)&W2b[cl * 1032 + kw0 + kk];
        uint4 u1 = *(const uint4*)&W2b[(cl + 8) * 1032 + kw0 + kk];
        fma8(za00, x0, x1, u0); fma8(za01, x0, x1, u1);
        fma8(za10, y0, y1, u0); fma8(za11, y0, y1, u1);
      }
      if (ch < 3) {
        int b4 = (ch + 1) * 4;
        *(float4*)&nbuf[r16 * 260 + c8] =
            make_float4(pf[b4].x, pf[b4].y, pf[b4 + 1].x, pf[b4 + 1].y);
        *(float4*)&nbuf[r16 * 260 + c8 + 4] =
            make_float4(pf[b4 + 2].x, pf[b4 + 2].y, pf[b4 + 3].x, pf[b4 + 3].y);
      }
      __syncthreads();
    }
    redFinishM(za00, za01, za10, za11, P0.Z2c, P1.Z2c, b2s, false);
  };

  // ---- H section (per pipe, wave w = row w, 4 h-dims per lane) ----
  auto hSec = [&](Pipe& P, int ci, int t, float* memCur, float4 hv) {
    const float* z2r = P.Z2c + w * H4;
    const int hd0 = lane * 4;
    float2 cv0 = gload2(z2r + 768 + hd0), cv1 = gload2(z2r + 768 + hd0 + 2);
    float cc[4] = {cv0.x, cv0.y, cv1.x, cv1.y};
    float s1 = cc[0] + cc[1] + cc[2] + cc[3];
    float s2 = cc[0] * cc[0] + cc[1] * cc[1] + cc[2] * cc[2] + cc[3] * cc[3];
#pragma unroll
    for (int m = 1; m < 64; m <<= 1) { s1 += __shfl_xor(s1, m, 64); s2 += __shfl_xor(s2, m, 64); }
    float mean = s1 * (1.f / 256.f);
    float inv = rsqrtf(s2 * (1.f / 256.f) - mean * mean + 1e-5f);
    float g[12];
#pragma unroll
    for (int j = 0; j < 6; ++j) {
      float2 v = gload2(z2r + hd0 * 3 + 2 * j);
      g[2 * j] = v.x; g[2 * j + 1] = v.y;
    }
    float4 vi4 = *(const float4*)&P.hloc[w * 260 + hd0];
    float4 xp4 = *(const float4*)&Xp[((size_t)t * BATCH + P.row0 + w) * HDIM + hd0];
    float viv[4] = {vi4.x, vi4.y, vi4.z, vi4.w};
    float xpv[4] = {xp4.x, xp4.y, xp4.z, xp4.w};
    float hivv[4] = {hv.x, hv.y, hv.z, hv.w};
    float cp = P.cpS[w * 8 + ci];
    float hn[4];
#pragma unroll
    for (int j = 0; j < 4; ++j) {
      int hd = hd0 + j;
      float z0 = g[3 * j], z1v = g[3 * j + 1], z2g = g[3 * j + 2];
      float gm = fmaxf(z0, fmaxf(z1v, z2g));
      float e0 = __expf(z0 - gm), e1 = __expf(z1v - gm), e2 = __expf(z2g - gm);
      float act = ftanh((cc[j] - mean) * inv * LNS_[hd] + LNB_[hd]);
      float hc = (e0 * viv[j] + e1 * hivv[j] + e2 * act) * __builtin_amdgcn_rcpf(e0 + e1 + e2);
      hn[j] = xpv[j] * (1.f - cp) + hc * cp;
    }
    *(float4*)&P.hloc[w * 260 + hd0] = make_float4(hn[0], hn[1], hn[2], hn[3]);
    if (lane == cg) {   // lane*4 == QC0: owner writes 4 cols
      float* mp = memCur + ((size_t)(P.row0 + w) * NS + ci) * HDIM + QC0;
      gstore2(mp, hn[0], hn[1]);
      gstore2(mp + 2, hn[2], hn[3]);
    }
  };

  // ---- cell section 2: window + H(ci) + merged Z1(ci+1) ----
  auto cellS2M = [&](int ci, int t, int phA, float* memCur) {
    const bool lastT = (t == T_LEN - 1);
    // hiv (Ast slot ci, row w) for both pipes before restage
    float4 hv0 = *(const float4*)&Ast0[w * 260 + lane * 4];
    float4 hv1 = *(const float4*)&Ast1[w * 260 + lane * 4];
    __syncthreads();
    if (ci < 7) {
      // restage both Ast = MbNew slot ci+1 (fully blended in P1)
      float* MbN0 = (t & 1) ? P0.MB1 : P0.MB0;
      float* MbN1 = (t & 1) ? P1.MB1 : P1.MB0;
      const int r16 = tid >> 5, c8 = (tid & 31) * 8, rr = r16 & 7;
      float* mb = (r16 < 8) ? MbN0 : MbN1;
      float* as = (r16 < 8) ? Ast0 : Ast1;
      const float* src = mb + (rr * NS + ci + 1) * HDIM + c8;
      float2 a0 = gload2(src), a1 = gload2(src + 2), a2 = gload2(src + 4), a3 = gload2(src + 6);
      *(float4*)&as[rr * 260 + c8] = make_float4(a0.x, a0.y, a1.x, a1.y);
      *(float4*)&as[rr * 260 + c8 + 4] = make_float4(a2.x, a2.y, a3.x, a3.y);
    } else if (!lastT) {
      // KPRE(s=6) from memCur slot 6 (visible: waited sigB(6) in cellS1(7))
      projK_G(memCur + ((size_t)(P0.row0 + w) * NS + 6) * HDIM, P0.KPRE + (w * 8 + 6) * HDIM + QC0);
      projK_G(memCur + ((size_t)(P1.row0 + w) * NS + 6) * HDIM, P1.KPRE + (w * 8 + 6) * HDIM + QC0);
    }
    __syncthreads();
    float b00 = 0.f, b01 = 0.f, b10 = 0.f, b11 = 0.f;
    if (ci < 7) z1HalfM(Ast0, Ast1, 256, b00, b01, b10, b11);   // Mn-half of Z1(ci+1)
    waitBoth(phA);
    hSec(P0, ci, t, memCur, hv0);
    hSec(P1, ci, t, memCur, hv1);
    __syncthreads();
    if (ci < 7) {
      z1HalfM(hloc0, hloc1, 0, b00, b01, b10, b11);   // h-half of Z1(ci+1)
      redFinishM(b00, b01, b10, b11, P0.Z1c, P1.Z1c, b1s, true);
    } else if (!lastT) {
      // KPRE(s=7) from new h (LDS) — pre-sigB
      projK_L(&hloc0[w * 260], P0.KPRE + (w * 8 + 7) * HDIM + QC0);
      projK_L(&hloc1[w * 260], P1.KPRE + (w * 8 + 7) * HDIM + QC0);
    }
  };

  // ---- B-window: S1a(t+1) pieces, drained by NEXT signal ----
  auto bWin = [&](Pipe& P, int ci, int t, float* memCur) {
    if (ci == 0) {
      projQ(Xp + ((size_t)(t + 1) * BATCH + P.row0 + w) * HDIM, P.QPRE + w * HDIM + QC0);
    } else if (ci <= 6) {
      const int s = ci - 1;   // memCur slot s visible (waited sigB(s) in cellS1(ci))
      projK_G(memCur + ((size_t)(P.row0 + w) * NS + s) * HDIM,
              P.KPRE + (w * 8 + s) * HDIM + QC0);
    } else {
      const int r = tid >> 6, c4 = (tid & 63) * 4;   // prestage hloc = Xp[t+1]
      *(float4*)&P.hloc[r * 260 + c4] =
          *(const float4*)&Xp[((size_t)(t + 1) * BATCH + P.row0 + r) * HDIM + c4];
    }
  };

  // ================= init + time loop =================
  __syncthreads();
  initPipe(P0); initPipe(P1);
  __syncthreads();
  s1aInit(P0); s1aInit(P1);
  int ph = 1;
  sigBoth(ph);
  waitBoth(ph);

  for (int t = 1; t < T_LEN; ++t) {
    const bool lastT = (t == T_LEN - 1);
    float* memCur = mem_out + (size_t)t * BATCH * NS * HDIM;
    p1Core(P0, t);
    p1Core(P1, t);
    {
      // merged Z1(0): Mn-half (Ast) + h-half (hloc)
      float a00 = 0.f, a01 = 0.f, a10 = 0.f, a11 = 0.f;
      z1HalfM(Ast0, Ast1, 256, a00, a01, a10, a11);
      z1HalfM(hloc0, hloc1, 0, a00, a01, a10, a11);
      redFinishM(a00, a01, a10, a11, P0.Z1c, P1.Z1c, b1s, true);
    }
    ++ph; sigBoth(ph);
    for (int ci = 0; ci < NS; ++ci) {
      const int phRdy = ph;
      cellS1M(phRdy);
      ++ph; sigBoth(ph);
      cellS2M(ci, t, ph, memCur);
      ++ph; sigBoth(ph);
      if (!lastT) { bWin(P0, ci, t, memCur); bWin(P1, ci, t, memCur); }
    }
    waitBoth(ph);
  }
}

extern "C" void kernel_launch(void* const* d_in, const int* in_sizes, int n_in,
                              void* d_out, int out_size, void* d_ws, size_t ws_size,
                              hipStream_t stream) {
  (void)in_sizes; (void)n_in; (void)out_size; (void)ws_size;
  const float* X     = (const float*)d_in[0];
  const float* Wp    = (const float*)d_in[3];
  const float* bp    = (const float*)d_in[4];
  const float* lns   = (const float*)d_in[5];
  const float* lnb   = (const float*)d_in[6];
  const float* Wq    = (const float*)d_in[7];
  const float* bq    = (const float*)d_in[8];
  const float* lnqs  = (const float*)d_in[9];
  const float* lnqb  = (const float*)d_in[10];
  const float* Wk    = (const float*)d_in[11];
  const float* bk    = (const float*)d_in[12];
  const float* lnks  = (const float*)d_in[13];
  const float* lnkb  = (const float*)d_in[14];
  const float* Wbeta = (const float*)d_in[15];
  const float* bbeta = (const float*)d_in[16];
  const float* W1    = (const float*)d_in[17];
  const float* b1    = (const float*)d_in[18];
  const float* W2    = (const float*)d_in[19];
  const float* b2    = (const float*)d_in[20];

  float* out       = (float*)d_out;
  float* out_xp    = out;
  float* out_mem   = out + (size_t)T_LEN * BATCH * HDIM;
  float* out_probs = out_mem + (size_t)T_LEN * BATCH * NS * HDIM;
  float* ws        = (float*)d_ws;

  hipLaunchKernelGGL(init_ctrl, dim3(4), dim3(256), 0, stream, (int*)d_ws);
  hipLaunchKernelGGL(xp_kernel, dim3(1024), dim3(256), 0, stream, X, Wp, bp, lns, lnb, out_xp);
  hipLaunchKernelGGL(omr_main, dim3(256), dim3(NTHR), 0, stream,
                     out_xp, Wq, bq, lnqs, lnqb, Wk, bk, lnks, lnkb, Wbeta, bbeta,
                     W1, b1, W2, b2, lns, lnb, out_mem, out_probs, ws);
}